// Round 1
// baseline (4300.104 us; speedup 1.0000x reference)
//
#include <hip/hip_runtime.h>

// LSAGEDirected: 3 directed mean-agg hops (concat in/out) + linear projection.
// N=50000 nodes, E=800000 edges, dims 64 ->128 ->256 ->512 -> proj 128.
#define NN 50000
#define NE 800000

__global__ void deg_kernel(const int* __restrict__ src, const int* __restrict__ dst,
                           float* __restrict__ deg) {
    int e = blockIdx.x * blockDim.x + threadIdx.x;
    if (e < NE) {
        atomicAdd(&deg[dst[e]], 1.0f);       // in-degree
        atomicAdd(&deg[NN + src[e]], 1.0f);  // out-degree
    }
}

__global__ void invert_kernel(float* __restrict__ deg) {
    int i = blockIdx.x * blockDim.x + threadIdx.x;
    if (i < 2 * NN) deg[i] = 1.0f / fmaxf(deg[i], 1.0f);
}

// One (edge, feature) pair per thread; D = input dim, output row stride 2D.
// Wave = one edge's 64 consecutive features -> coalesced loads, line-local atomics.
template <int D>
__global__ void scatter_kernel(const float* __restrict__ h,
                               const int* __restrict__ src,
                               const int* __restrict__ dst,
                               float* __restrict__ out) {
    unsigned idx = blockIdx.x * blockDim.x + threadIdx.x;
    if (idx >= (unsigned)NE * D) return;
    unsigned e = idx / D;           // D is power of two -> shift
    unsigned f = idx - e * D;
    int s = src[e], d = dst[e];
    atomicAdd(&out[(unsigned)d * (2 * D) + f],     h[(unsigned)s * D + f]); // in-agg at dst
    atomicAdd(&out[(unsigned)s * (2 * D) + D + f], h[(unsigned)d * D + f]); // out-agg at src
}

// Multiply first half of each row by inv_in[node], second half by inv_out[node].
template <int D2>
__global__ void scale_kernel(float* __restrict__ h, const float* __restrict__ inv) {
    unsigned idx = blockIdx.x * blockDim.x + threadIdx.x;
    if (idx >= (unsigned)NN * D2) return;
    unsigned node = idx / D2;
    unsigned f = idx - node * D2;
    h[idx] *= inv[(f < (D2 / 2) ? 0u : (unsigned)NN) + node];
}

// out[m][o] = b[o] + sum_k h[m][k] * W[o][k]; M=50000, K=512, Nout=128.
// Wave lanes vary o for fixed m: h-reads broadcast, W (256KB) stays in L2.
__global__ void gemm_kernel(const float* __restrict__ h, const float* __restrict__ W,
                            const float* __restrict__ b, float* __restrict__ out) {
    int idx = blockIdx.x * blockDim.x + threadIdx.x;
    if (idx >= NN * 128) return;
    int m = idx >> 7, o = idx & 127;
    const float4* hr = (const float4*)(h + (size_t)m * 512);
    const float4* wr = (const float4*)(W + (size_t)o * 512);
    float a0 = 0.f, a1 = 0.f, a2 = 0.f, a3 = 0.f;
#pragma unroll 8
    for (int k = 0; k < 128; ++k) {
        float4 a = hr[k], w = wr[k];
        a0 += a.x * w.x; a1 += a.y * w.y; a2 += a.z * w.z; a3 += a.w * w.w;
    }
    out[idx] = (a0 + a1) + (a2 + a3) + b[o];
}

extern "C" void kernel_launch(void* const* d_in, const int* in_sizes, int n_in,
                              void* d_out, int out_size, void* d_ws, size_t ws_size,
                              hipStream_t stream) {
    const float* feature = (const float*)d_in[0];
    const int*   edges   = (const int*)d_in[1];   // [2, NE] row-major: src row then dst row
    const float* W       = (const float*)d_in[2];
    const float* b       = (const float*)d_in[3];
    const int* src = edges;
    const int* dst = edges + NE;
    float* out = (float*)d_out;
    float* ws  = (float*)d_ws;

    // Workspace layout (floats): [inv_in | inv_out | h2 (NN*256) | h3 (NN*512)]
    float* deg = ws;                      // 2*NN
    float* h2  = ws + 2 * NN;             // NN*256
    float* h3  = h2 + (size_t)NN * 256;   // NN*512
    float* h1  = out;                     // NN*128 == out_size, overwritten by GEMM

    // degrees -> inverse
    hipMemsetAsync(deg, 0, 2 * NN * sizeof(float), stream);
    deg_kernel<<<(NE + 255) / 256, 256, 0, stream>>>(src, dst, deg);
    invert_kernel<<<(2 * NN + 255) / 256, 256, 0, stream>>>(deg);

    // hop 1: feature (64) -> h1 (128)
    hipMemsetAsync(h1, 0, (size_t)NN * 128 * sizeof(float), stream);
    scatter_kernel<64><<<((size_t)NE * 64) / 256, 256, 0, stream>>>(feature, src, dst, h1);
    scale_kernel<128><<<(NN * 128 + 255) / 256, 256, 0, stream>>>(h1, deg);

    // hop 2: h1 (128) -> h2 (256)
    hipMemsetAsync(h2, 0, (size_t)NN * 256 * sizeof(float), stream);
    scatter_kernel<128><<<((size_t)NE * 128) / 256, 256, 0, stream>>>(h1, src, dst, h2);
    scale_kernel<256><<<(NN * 256 + 255) / 256, 256, 0, stream>>>(h2, deg);

    // hop 3: h2 (256) -> h3 (512)
    hipMemsetAsync(h3, 0, (size_t)NN * 512 * sizeof(float), stream);
    scatter_kernel<256><<<((size_t)NE * 256) / 256, 256, 0, stream>>>(h2, src, dst, h3);
    scale_kernel<512><<<(NN * 512 + 255) / 256, 256, 0, stream>>>(h3, deg);

    // projection: h3 @ W^T + b
    gemm_kernel<<<(NN * 128 + 255) / 256, 256, 0, stream>>>(h3, W, b, out);
}

// Round 3
// 833.201 us; speedup vs baseline: 5.1609x; 5.1609x over previous
//
#include <hip/hip_runtime.h>

// LSAGEDirected: 3 directed mean-agg hops (concat in/out) + linear projection.
// R2: CSR gather (no float atomics) + W folded before hop 3 + tiled GEMM.
// N=50000 nodes, E=800000 edges: 64 ->128 ->256 --GEMM--> 256 --agg--> 128.
#define NN 50000
#define NE 800000

// ---------- degree count (int atomics) ----------
__global__ void count_kernel(const int* __restrict__ src, const int* __restrict__ dst,
                             int* __restrict__ deg_in, int* __restrict__ deg_out) {
    int e = blockIdx.x * blockDim.x + threadIdx.x;
    if (e < NE) {
        atomicAdd(&deg_in[dst[e]], 1);
        atomicAdd(&deg_out[src[e]], 1);
    }
}

__global__ void inv_kernel(const int* __restrict__ deg_in, const int* __restrict__ deg_out,
                           float* __restrict__ inv_in, float* __restrict__ inv_out) {
    int i = blockIdx.x * blockDim.x + threadIdx.x;
    if (i < NN) {
        inv_in[i]  = 1.0f / fmaxf((float)deg_in[i], 1.0f);
        inv_out[i] = 1.0f / fmaxf((float)deg_out[i], 1.0f);
    }
}

// ---------- exclusive scan (single block per array; blockIdx selects array) ----------
__global__ void scan_kernel(const int* __restrict__ deg_in, int* __restrict__ row_in,
                            const int* __restrict__ deg_out, int* __restrict__ row_out) {
    const int* deg = (blockIdx.x == 0) ? deg_in : deg_out;
    int* row       = (blockIdx.x == 0) ? row_in : row_out;
    __shared__ int sh[1024];
    __shared__ int run;
    int tid = threadIdx.x;
    if (tid == 0) run = 0;
    __syncthreads();
    for (int base = 0; base < NN; base += 1024) {
        int i = base + tid;
        int v = (i < NN) ? deg[i] : 0;
        sh[tid] = v;
        __syncthreads();
        int x = v;
        for (int off = 1; off < 1024; off <<= 1) {
            int y = (tid >= off) ? sh[tid - off] : 0;
            __syncthreads();
            x += y;
            sh[tid] = x;
            __syncthreads();
        }
        if (i < NN) row[i] = run + x - v;   // exclusive
        __syncthreads();
        if (tid == 0) run += sh[1023];
        __syncthreads();
    }
    if (tid == 0) row[NN] = run;
}

// ---------- CSR fill ----------
__global__ void fill_kernel(const int* __restrict__ src, const int* __restrict__ dst,
                            const int* __restrict__ row_in, const int* __restrict__ row_out,
                            int* __restrict__ cur_in, int* __restrict__ cur_out,
                            int* __restrict__ csr_in, int* __restrict__ csr_out) {
    int e = blockIdx.x * blockDim.x + threadIdx.x;
    if (e < NE) {
        int s = src[e], d = dst[e];
        csr_in[row_in[d] + atomicAdd(&cur_in[d], 1)]  = s;   // in-nbrs of d are srcs
        csr_out[row_out[s] + atomicAdd(&cur_out[s], 1)] = d; // out-nbrs of s are dsts
    }
}

// ---------- gather hop: h[DIN] -> out[2*DIN] (in-half | out-half), mean-scaled ----------
// thread = (node, col); wave covers 64 consecutive cols of one node -> coalesced nbr-row reads.
template <int DIN>
__global__ void gather_kernel(const float* __restrict__ h,
                              const int* __restrict__ row_in, const int* __restrict__ csr_in,
                              const int* __restrict__ row_out, const int* __restrict__ csr_out,
                              const float* __restrict__ inv_in, const float* __restrict__ inv_out,
                              float* __restrict__ out) {
    unsigned idx = blockIdx.x * blockDim.x + threadIdx.x;
    if (idx >= (unsigned)NN * 2 * DIN) return;
    unsigned n = idx / (2 * DIN);
    unsigned c = idx - n * (2 * DIN);
    bool is_out = (c >= DIN);
    unsigned f = is_out ? c - DIN : c;
    const int* row = is_out ? row_out : row_in;
    const int* csr = is_out ? csr_out : csr_in;
    float invv = is_out ? inv_out[n] : inv_in[n];
    int beg = row[n], end = row[n + 1];
    float acc = 0.f;
    int j = beg;
    for (; j + 1 < end; j += 2) {   // 2 independent loads in flight
        int n0 = csr[j], n1 = csr[j + 1];
        acc += h[(size_t)n0 * DIN + f] + h[(size_t)n1 * DIN + f];
    }
    if (j < end) acc += h[(size_t)csr[j] * DIN + f];
    out[(size_t)n * (2 * DIN) + c] = acc * invv;
}

// ---------- B prep: B[k][j] (256x256) from W[128][512]; j<128 -> Wi, else Wo ----------
__global__ void prep_b_kernel(const float* __restrict__ W, float* __restrict__ B) {
    int idx = blockIdx.x * blockDim.x + threadIdx.x;  // 65536
    int k = idx >> 8, jc = idx & 255;
    B[idx] = (jc < 128) ? W[jc * 512 + k] : W[(jc - 128) * 512 + 256 + k];
}

// ---------- tiled GEMM: C[NN][256] = A[NN][256] * B[256][256] ----------
// block 256 thr = 16x16, tile 64x64, 4x4 micro-tile per thread.
__global__ void gemm_kernel(const float* __restrict__ A, const float* __restrict__ B,
                            float* __restrict__ C) {
    __shared__ float As[16][64 + 1];  // [k][m], padded
    __shared__ float Bs[16][64];      // [k][n]
    int tx = threadIdx.x & 15, ty = threadIdx.x >> 4;
    int m0 = blockIdx.x * 64;
    int n0 = blockIdx.y * 64;
    float acc[4][4] = {};
    for (int k0 = 0; k0 < 256; k0 += 16) {
        {   // A tile: 64 m x 16 k; thread loads float4 along k, stores transposed
            int r = threadIdx.x >> 2;
            int kq = (threadIdx.x & 3) * 4;
            int m = m0 + r;
            float4 v = (m < NN) ? *(const float4*)&A[(size_t)m * 256 + k0 + kq]
                                : make_float4(0.f, 0.f, 0.f, 0.f);
            As[kq + 0][r] = v.x;
            As[kq + 1][r] = v.y;
            As[kq + 2][r] = v.z;
            As[kq + 3][r] = v.w;
        }
        {   // B tile: 16 k x 64 n; coalesced float4
            int kr = threadIdx.x >> 4;
            int nc = (threadIdx.x & 15) * 4;
            *(float4*)&Bs[kr][nc] = *(const float4*)&B[(size_t)(k0 + kr) * 256 + n0 + nc];
        }
        __syncthreads();
#pragma unroll
        for (int k = 0; k < 16; ++k) {
            float a[4], bb[4];
#pragma unroll
            for (int i = 0; i < 4; ++i) a[i] = As[k][ty * 4 + i];
#pragma unroll
            for (int jj = 0; jj < 4; ++jj) bb[jj] = Bs[k][tx * 4 + jj];
#pragma unroll
            for (int i = 0; i < 4; ++i)
#pragma unroll
                for (int jj = 0; jj < 4; ++jj) acc[i][jj] += a[i] * bb[jj];
        }
        __syncthreads();
    }
#pragma unroll
    for (int i = 0; i < 4; ++i) {
        int m = m0 + ty * 4 + i;
        if (m < NN) {
#pragma unroll
            for (int jj = 0; jj < 4; ++jj)
                C[(size_t)m * 256 + n0 + tx * 4 + jj] = acc[i][jj];
        }
    }
}

// ---------- final hop + bias: out[n][o] = inv_in*sum_in g[.][o] + inv_out*sum_out g[.][128+o] + b[o]
__global__ void final_kernel(const float* __restrict__ g,
                             const int* __restrict__ row_in, const int* __restrict__ csr_in,
                             const int* __restrict__ row_out, const int* __restrict__ csr_out,
                             const float* __restrict__ inv_in, const float* __restrict__ inv_out,
                             const float* __restrict__ b, float* __restrict__ out) {
    unsigned idx = blockIdx.x * blockDim.x + threadIdx.x;
    if (idx >= (unsigned)NN * 128) return;
    unsigned n = idx >> 7, o = idx & 127;
    float ai = 0.f, ao = 0.f;
    {
        int beg = row_in[n], end = row_in[n + 1], j = beg;
        for (; j + 1 < end; j += 2) {
            int n0 = csr_in[j], n1 = csr_in[j + 1];
            ai += g[(size_t)n0 * 256 + o] + g[(size_t)n1 * 256 + o];
        }
        if (j < end) ai += g[(size_t)csr_in[j] * 256 + o];
    }
    {
        int beg = row_out[n], end = row_out[n + 1], j = beg;
        for (; j + 1 < end; j += 2) {
            int n0 = csr_out[j], n1 = csr_out[j + 1];
            ao += g[(size_t)n0 * 256 + 128 + o] + g[(size_t)n1 * 256 + 128 + o];
        }
        if (j < end) ao += g[(size_t)csr_out[j] * 256 + 128 + o];
    }
    out[idx] = ai * inv_in[n] + ao * inv_out[n] + b[o];
}

extern "C" void kernel_launch(void* const* d_in, const int* in_sizes, int n_in,
                              void* d_out, int out_size, void* d_ws, size_t ws_size,
                              hipStream_t stream) {
    const float* feature = (const float*)d_in[0];
    const int*   edges   = (const int*)d_in[1];   // [2, NE]: src row then dst row
    const float* W       = (const float*)d_in[2];
    const float* b       = (const float*)d_in[3];
    const int* src = edges;
    const int* dst = edges + NE;
    float* out = (float*)d_out;
    float* ws  = (float*)d_ws;

    // Workspace layout; float4-accessed buffers first (16B alignment). ~111 MB total.
    float* h2      = ws;                      // NN*256 floats
    float* g       = h2 + (size_t)NN * 256;   // NN*256 floats
    float* Bmat    = g + (size_t)NN * 256;    // 65536 floats
    float* inv_in  = Bmat + 65536;            // NN floats
    float* inv_out = inv_in + NN;             // NN floats
    int* deg_in    = (int*)(inv_out + NN);    // NN ints (start of one contiguous memset)
    int* deg_out   = deg_in + NN;             // NN ints
    int* cur_in    = deg_out + NN;            // NN ints
    int* cur_out   = cur_in + NN;             // NN ints (end of memset region)
    int* row_in    = cur_out + NN;            // NN+1 ints
    int* row_out   = row_in + NN + 1;         // NN+1 ints
    int* csr_in    = row_out + NN + 1;        // NE ints
    int* csr_out   = csr_in + NE;             // NE ints
    float* h1 = out;                          // NN*128 lives in d_out; overwritten later

    (void)hipMemsetAsync(deg_in, 0, (size_t)4 * NN * sizeof(int), stream);
    count_kernel<<<(NE + 255) / 256, 256, 0, stream>>>(src, dst, deg_in, deg_out);
    inv_kernel<<<(NN + 255) / 256, 256, 0, stream>>>(deg_in, deg_out, inv_in, inv_out);
    scan_kernel<<<2, 1024, 0, stream>>>(deg_in, row_in, deg_out, row_out);
    fill_kernel<<<(NE + 255) / 256, 256, 0, stream>>>(src, dst, row_in, row_out,
                                                      cur_in, cur_out, csr_in, csr_out);

    // hop 1: X(64) -> h1(128)
    gather_kernel<64><<<(NN * 128) / 256, 256, 0, stream>>>(
        feature, row_in, csr_in, row_out, csr_out, inv_in, inv_out, h1);
    // hop 2: h1(128) -> h2(256)
    gather_kernel<128><<<(NN * 256) / 256, 256, 0, stream>>>(
        h1, row_in, csr_in, row_out, csr_out, inv_in, inv_out, h2);
    // projection folded before hop 3: g = h2 @ [Wi|Wo]^T  (50000x256 @ 256x256)
    prep_b_kernel<<<256, 256, 0, stream>>>(W, Bmat);
    dim3 ggrid((NN + 63) / 64, 4);
    gemm_kernel<<<ggrid, 256, 0, stream>>>(h2, Bmat, g);
    // hop 3 + bias: aggregate g rows -> out
    final_kernel<<<(NN * 128) / 256, 256, 0, stream>>>(
        g, row_in, csr_in, row_out, csr_out, inv_in, inv_out, b, out);
}

// Round 4
// 612.554 us; speedup vs baseline: 7.0200x; 1.3602x over previous
//
#include <hip/hip_runtime.h>

// LSAGEDirected: 3 directed mean-agg hops (concat in/out) + linear projection.
// R3: float2+unroll4 gathers, 3-phase scan, inv folded into gathers, b128 GEMM LDS.
// N=50000 nodes, E=800000 edges: 64 ->128 ->256 --GEMM--> 256 --agg--> 128.
#define NN 50000
#define NE 800000

// ---------- degree count (int atomics) ----------
__global__ void count_kernel(const int* __restrict__ src, const int* __restrict__ dst,
                             int* __restrict__ deg_in, int* __restrict__ deg_out) {
    int e = blockIdx.x * blockDim.x + threadIdx.x;
    if (e < NE) {
        atomicAdd(&deg_in[dst[e]], 1);
        atomicAdd(&deg_out[src[e]], 1);
    }
}

// ---------- 3-phase exclusive scan over deg_in and deg_out (blockIdx.y selects) ----------
__global__ void scan_block_kernel(const int* __restrict__ deg_in, int* __restrict__ row_in,
                                  const int* __restrict__ deg_out, int* __restrict__ row_out,
                                  int* __restrict__ partials) {
    const int* deg = blockIdx.y ? deg_out : deg_in;
    int* row       = blockIdx.y ? row_out : row_in;
    __shared__ int sh[1024];
    int i = blockIdx.x * 1024 + threadIdx.x;
    int v = (i < NN) ? deg[i] : 0;
    sh[threadIdx.x] = v;
    __syncthreads();
    int x = v;
    for (int off = 1; off < 1024; off <<= 1) {
        int y = (threadIdx.x >= off) ? sh[threadIdx.x - off] : 0;
        __syncthreads();
        x += y;
        sh[threadIdx.x] = x;
        __syncthreads();
    }
    if (i < NN) row[i] = x - v;   // block-local exclusive
    if (threadIdx.x == 1023) partials[blockIdx.y * 64 + blockIdx.x] = x;
}

__global__ void scan_partials_kernel(int* __restrict__ partials,
                                     int* __restrict__ row_in, int* __restrict__ row_out) {
    int a = threadIdx.x;   // one thread per array; 49 partials each — trivial
    if (a < 2) {
        int* p = partials + a * 64;
        int run = 0;
        for (int i = 0; i < 49; ++i) { int v = p[i]; p[i] = run; run += v; }
        (a ? row_out : row_in)[NN] = run;
    }
}

__global__ void scan_add_kernel(int* __restrict__ row_in, int* __restrict__ row_out,
                                const int* __restrict__ partials) {
    int i = blockIdx.x * 1024 + threadIdx.x;
    if (i < NN) (blockIdx.y ? row_out : row_in)[i] += partials[blockIdx.y * 64 + blockIdx.x];
}

// ---------- CSR fill ----------
__global__ void fill_kernel(const int* __restrict__ src, const int* __restrict__ dst,
                            const int* __restrict__ row_in, const int* __restrict__ row_out,
                            int* __restrict__ cur_in, int* __restrict__ cur_out,
                            int* __restrict__ csr_in, int* __restrict__ csr_out) {
    int e = blockIdx.x * blockDim.x + threadIdx.x;
    if (e < NE) {
        int s = src[e], d = dst[e];
        csr_in[row_in[d] + atomicAdd(&cur_in[d], 1)]  = s;   // in-nbrs of d are srcs
        csr_out[row_out[s] + atomicAdd(&cur_out[s], 1)] = d; // out-nbrs of s are dsts
    }
}

// ---------- gather hop: h[DIN] -> out[2*DIN], mean-scaled; float2 lanes, unroll 4 ----------
template <int DIN>
__global__ void gather_kernel(const float2* __restrict__ h,
                              const int* __restrict__ row_in, const int* __restrict__ csr_in,
                              const int* __restrict__ row_out, const int* __restrict__ csr_out,
                              float2* __restrict__ out) {
    constexpr int S2 = DIN / 2;                         // float2 per input row
    unsigned idx = blockIdx.x * blockDim.x + threadIdx.x;  // NN * DIN threads
    if (idx >= (unsigned)NN * DIN) return;
    unsigned n = idx / DIN;
    unsigned r = idx - n * DIN;                         // [0, 2*S2)
    bool is_out = (r >= S2);
    unsigned f = is_out ? r - S2 : r;
    const int* row = is_out ? row_out : row_in;
    const int* csr = is_out ? csr_out : csr_in;
    int beg = row[n], end = row[n + 1];
    float invv = 1.0f / fmaxf((float)(end - beg), 1.0f);
    float ax = 0.f, ay = 0.f;
    int j = beg;
    for (; j + 3 < end; j += 4) {                       // 4 independent loads in flight
        int n0 = csr[j], n1 = csr[j + 1], n2 = csr[j + 2], n3 = csr[j + 3];
        float2 v0 = h[(size_t)n0 * S2 + f], v1 = h[(size_t)n1 * S2 + f];
        float2 v2 = h[(size_t)n2 * S2 + f], v3 = h[(size_t)n3 * S2 + f];
        ax += (v0.x + v1.x) + (v2.x + v3.x);
        ay += (v0.y + v1.y) + (v2.y + v3.y);
    }
    for (; j < end; ++j) { float2 v = h[(size_t)csr[j] * S2 + f]; ax += v.x; ay += v.y; }
    out[(size_t)n * DIN + r] = make_float2(ax * invv, ay * invv);
}

// ---------- B prep: B[k][j] (256x256) from W[128][512]; j<128 -> Wi, else Wo ----------
__global__ void prep_b_kernel(const float* __restrict__ W, float* __restrict__ B) {
    int idx = blockIdx.x * blockDim.x + threadIdx.x;  // 65536
    int k = idx >> 8, jc = idx & 255;
    B[idx] = (jc < 128) ? W[jc * 512 + k] : W[(jc - 128) * 512 + 256 + k];
}

// ---------- tiled GEMM: C[NN][256] = A[NN][256] * B[256][256] ----------
// block 256 thr = 16x16, tile 64x64, 4x4 micro-tile, b128 LDS reads.
__global__ void gemm_kernel(const float* __restrict__ A, const float* __restrict__ B,
                            float* __restrict__ C) {
    __shared__ __align__(16) float As[16][68];  // [k][m], 272B row stride keeps 16B align
    __shared__ __align__(16) float Bs[16][64];  // [k][n]
    int tx = threadIdx.x & 15, ty = threadIdx.x >> 4;
    int m0 = blockIdx.x * 64;
    int n0 = blockIdx.y * 64;
    float acc[4][4] = {};
    for (int k0 = 0; k0 < 256; k0 += 16) {
        {   // A tile: 64 m x 16 k; float4 along k, stored transposed
            int r = threadIdx.x >> 2;
            int kq = (threadIdx.x & 3) * 4;
            int m = m0 + r;
            float4 v = (m < NN) ? *(const float4*)&A[(size_t)m * 256 + k0 + kq]
                                : make_float4(0.f, 0.f, 0.f, 0.f);
            As[kq + 0][r] = v.x;
            As[kq + 1][r] = v.y;
            As[kq + 2][r] = v.z;
            As[kq + 3][r] = v.w;
        }
        {   // B tile: 16 k x 64 n; coalesced float4
            int kr = threadIdx.x >> 4;
            int nc = (threadIdx.x & 15) * 4;
            *(float4*)&Bs[kr][nc] = *(const float4*)&B[(size_t)(k0 + kr) * 256 + n0 + nc];
        }
        __syncthreads();
#pragma unroll
        for (int k = 0; k < 16; ++k) {
            float4 av = *(const float4*)&As[k][ty * 4];
            float4 bv = *(const float4*)&Bs[k][tx * 4];
            float a[4] = {av.x, av.y, av.z, av.w};
            float bb[4] = {bv.x, bv.y, bv.z, bv.w};
#pragma unroll
            for (int i = 0; i < 4; ++i)
#pragma unroll
                for (int jj = 0; jj < 4; ++jj) acc[i][jj] += a[i] * bb[jj];
        }
        __syncthreads();
    }
#pragma unroll
    for (int i = 0; i < 4; ++i) {
        int m = m0 + ty * 4 + i;
        if (m < NN) {
#pragma unroll
            for (int jj = 0; jj < 4; ++jj)
                C[(size_t)m * 256 + n0 + tx * 4 + jj] = acc[i][jj];
        }
    }
}

// ---------- final hop + bias: float2 lanes; wave = one node (uniform lists) ----------
__global__ void final_kernel(const float2* __restrict__ g,
                             const int* __restrict__ row_in, const int* __restrict__ csr_in,
                             const int* __restrict__ row_out, const int* __restrict__ csr_out,
                             const float2* __restrict__ b2, float2* __restrict__ out) {
    unsigned idx = blockIdx.x * blockDim.x + threadIdx.x;  // NN * 64
    if (idx >= (unsigned)NN * 64) return;
    unsigned n = idx >> 6, f = idx & 63;
    float ox = 0.f, oy = 0.f;
    {   // in-direction: first 128 cols of g -> float2 slots [0,64)
        int beg = row_in[n], end = row_in[n + 1];
        float inv = 1.0f / fmaxf((float)(end - beg), 1.0f);
        float sx = 0.f, sy = 0.f;
        int j = beg;
        for (; j + 3 < end; j += 4) {
            int n0 = csr_in[j], n1 = csr_in[j + 1], n2 = csr_in[j + 2], n3 = csr_in[j + 3];
            float2 v0 = g[(size_t)n0 * 128 + f], v1 = g[(size_t)n1 * 128 + f];
            float2 v2 = g[(size_t)n2 * 128 + f], v3 = g[(size_t)n3 * 128 + f];
            sx += (v0.x + v1.x) + (v2.x + v3.x);
            sy += (v0.y + v1.y) + (v2.y + v3.y);
        }
        for (; j < end; ++j) { float2 v = g[(size_t)csr_in[j] * 128 + f]; sx += v.x; sy += v.y; }
        ox = sx * inv; oy = sy * inv;
    }
    {   // out-direction: last 128 cols of g -> float2 slots [64,128)
        int beg = row_out[n], end = row_out[n + 1];
        float inv = 1.0f / fmaxf((float)(end - beg), 1.0f);
        float sx = 0.f, sy = 0.f;
        int j = beg;
        for (; j + 3 < end; j += 4) {
            int n0 = csr_out[j], n1 = csr_out[j + 1], n2 = csr_out[j + 2], n3 = csr_out[j + 3];
            float2 v0 = g[(size_t)n0 * 128 + 64 + f], v1 = g[(size_t)n1 * 128 + 64 + f];
            float2 v2 = g[(size_t)n2 * 128 + 64 + f], v3 = g[(size_t)n3 * 128 + 64 + f];
            sx += (v0.x + v1.x) + (v2.x + v3.x);
            sy += (v0.y + v1.y) + (v2.y + v3.y);
        }
        for (; j < end; ++j) { float2 v = g[(size_t)csr_out[j] * 128 + 64 + f]; sx += v.x; sy += v.y; }
        ox += sx * inv; oy += sy * inv;
    }
    float2 bb = b2[f];
    out[(size_t)n * 64 + f] = make_float2(ox + bb.x, oy + bb.y);
}

extern "C" void kernel_launch(void* const* d_in, const int* in_sizes, int n_in,
                              void* d_out, int out_size, void* d_ws, size_t ws_size,
                              hipStream_t stream) {
    const float* feature = (const float*)d_in[0];
    const int*   edges   = (const int*)d_in[1];   // [2, NE]: src row then dst row
    const float* W       = (const float*)d_in[2];
    const float* b       = (const float*)d_in[3];
    const int* src = edges;
    const int* dst = edges + NE;
    float* out = (float*)d_out;
    float* ws  = (float*)d_ws;

    // Workspace layout; vector-accessed buffers first (16B alignment). ~110 MB total.
    float* h2    = ws;                       // NN*256 floats
    float* g     = h2 + (size_t)NN * 256;    // NN*256 floats
    float* Bmat  = g + (size_t)NN * 256;     // 65536 floats
    int* deg_in  = (int*)(Bmat + 65536);     // NN ints (start of contiguous memset region)
    int* deg_out = deg_in + NN;              // NN ints
    int* cur_in  = deg_out + NN;             // NN ints
    int* cur_out = cur_in + NN;              // NN ints (end of memset region)
    int* row_in  = cur_out + NN;             // NN+1 ints
    int* row_out = row_in + NN + 1;          // NN+1 ints
    int* csr_in  = row_out + NN + 1;         // NE ints
    int* csr_out = csr_in + NE;              // NE ints
    int* partials = csr_out + NE;            // 128 ints
    float* h1 = out;                         // NN*128 lives in d_out; overwritten by final

    (void)hipMemsetAsync(deg_in, 0, (size_t)4 * NN * sizeof(int), stream);
    count_kernel<<<(NE + 255) / 256, 256, 0, stream>>>(src, dst, deg_in, deg_out);
    dim3 sgrid(49, 2);
    scan_block_kernel<<<sgrid, 1024, 0, stream>>>(deg_in, row_in, deg_out, row_out, partials);
    scan_partials_kernel<<<1, 64, 0, stream>>>(partials, row_in, row_out);
    scan_add_kernel<<<sgrid, 1024, 0, stream>>>(row_in, row_out, partials);
    fill_kernel<<<(NE + 255) / 256, 256, 0, stream>>>(src, dst, row_in, row_out,
                                                      cur_in, cur_out, csr_in, csr_out);

    // hop 1: X(64) -> h1(128)
    gather_kernel<64><<<(NN * 64) / 256, 256, 0, stream>>>(
        (const float2*)feature, row_in, csr_in, row_out, csr_out, (float2*)h1);
    // hop 2: h1(128) -> h2(256)
    gather_kernel<128><<<(NN * 128) / 256, 256, 0, stream>>>(
        (const float2*)h1, row_in, csr_in, row_out, csr_out, (float2*)h2);
    // projection folded before hop 3: g = h2 @ [Wi|Wo]^T  (50000x256 @ 256x256)
    prep_b_kernel<<<256, 256, 0, stream>>>(W, Bmat);
    dim3 ggrid((NN + 63) / 64, 4);
    gemm_kernel<<<ggrid, 256, 0, stream>>>(h2, Bmat, g);
    // hop 3 + bias: aggregate g rows -> out
    final_kernel<<<(NN * 64) / 256, 256, 0, stream>>>(
        (const float2*)g, row_in, csr_in, row_out, csr_out, (const float2*)b, (float2*)out);
}

// Round 5
// 576.962 us; speedup vs baseline: 7.4530x; 1.0617x over previous
//
#include <hip/hip_runtime.h>

// LSAGEDirected: 3 directed mean-agg hops (concat in/out) + linear projection.
// R4: XCD-sliced CSR build (kills write-amplification), float4 gathers.
// N=50000 nodes, E=800000 edges: 64 ->128 ->256 --GEMM--> 256 --agg--> 128.
#define NN 50000
#define NE 800000
#define NSLICE 8
#define SLICE_N 6250     // NN / NSLICE
#define NCHUNK 128       // edge chunks per slice
#define CHUNK_E 6250     // NE / NCHUNK

// ---------- sliced degree count: block handles nodes in slice (blockIdx&7) only ----------
// Slice's deg lines are written by one slice-group of blocks (heuristically one XCD's L2).
__global__ void count_sliced_kernel(const int* __restrict__ src, const int* __restrict__ dst,
                                    int* __restrict__ deg_in, int* __restrict__ deg_out) {
    int slice = blockIdx.x & (NSLICE - 1);
    int chunk = blockIdx.x >> 3;
    int lo = slice * SLICE_N, hi = lo + SLICE_N;   // NN = 8*6250 exactly
    int e1 = min((chunk + 1) * CHUNK_E, NE);
    for (int e = chunk * CHUNK_E + threadIdx.x; e < e1; e += 256) {
        int s = src[e], d = dst[e];
        if (d >= lo && d < hi) atomicAdd(&deg_in[d], 1);
        if (s >= lo && s < hi) atomicAdd(&deg_out[s], 1);
    }
}

// ---------- 3-phase exclusive scan over deg_in and deg_out (blockIdx.y selects) ----------
__global__ void scan_block_kernel(const int* __restrict__ deg_in, int* __restrict__ row_in,
                                  const int* __restrict__ deg_out, int* __restrict__ row_out,
                                  int* __restrict__ partials) {
    const int* deg = blockIdx.y ? deg_out : deg_in;
    int* row       = blockIdx.y ? row_out : row_in;
    __shared__ int sh[1024];
    int i = blockIdx.x * 1024 + threadIdx.x;
    int v = (i < NN) ? deg[i] : 0;
    sh[threadIdx.x] = v;
    __syncthreads();
    int x = v;
    for (int off = 1; off < 1024; off <<= 1) {
        int y = (threadIdx.x >= off) ? sh[threadIdx.x - off] : 0;
        __syncthreads();
        x += y;
        sh[threadIdx.x] = x;
        __syncthreads();
    }
    if (i < NN) row[i] = x - v;   // block-local exclusive
    if (threadIdx.x == 1023) partials[blockIdx.y * 64 + blockIdx.x] = x;
}

__global__ void scan_partials_kernel(int* __restrict__ partials,
                                     int* __restrict__ row_in, int* __restrict__ row_out) {
    int a = threadIdx.x;
    if (a < 2) {
        int* p = partials + a * 64;
        int run = 0;
        for (int i = 0; i < 49; ++i) { int v = p[i]; p[i] = run; run += v; }
        (a ? row_out : row_in)[NN] = run;
    }
}

__global__ void scan_add_kernel(int* __restrict__ row_in, int* __restrict__ row_out,
                                const int* __restrict__ partials) {
    int i = blockIdx.x * 1024 + threadIdx.x;
    if (i < NN) (blockIdx.y ? row_out : row_in)[i] += partials[blockIdx.y * 64 + blockIdx.x];
}

// ---------- sliced CSR fill: same slicing; csr/cur lines stay slice-local ----------
__global__ void fill_sliced_kernel(const int* __restrict__ src, const int* __restrict__ dst,
                                   const int* __restrict__ row_in, const int* __restrict__ row_out,
                                   int* __restrict__ cur_in, int* __restrict__ cur_out,
                                   int* __restrict__ csr_in, int* __restrict__ csr_out) {
    int slice = blockIdx.x & (NSLICE - 1);
    int chunk = blockIdx.x >> 3;
    int lo = slice * SLICE_N, hi = lo + SLICE_N;
    int e1 = min((chunk + 1) * CHUNK_E, NE);
    for (int e = chunk * CHUNK_E + threadIdx.x; e < e1; e += 256) {
        int s = src[e], d = dst[e];
        if (d >= lo && d < hi) csr_in[row_in[d] + atomicAdd(&cur_in[d], 1)] = s;
        if (s >= lo && s < hi) csr_out[row_out[s] + atomicAdd(&cur_out[s], 1)] = d;
    }
}

// ---------- gather hop: h[DIN] -> out[2*DIN], mean-scaled; float4 lanes, unroll 4 ----------
template <int DIN>
__global__ void gather_kernel(const float4* __restrict__ h,
                              const int* __restrict__ row_in, const int* __restrict__ csr_in,
                              const int* __restrict__ row_out, const int* __restrict__ csr_out,
                              float4* __restrict__ out) {
    constexpr int S4 = DIN / 4;                            // float4 per input row
    unsigned idx = blockIdx.x * blockDim.x + threadIdx.x;  // NN * DIN/2 threads
    if (idx >= (unsigned)NN * (DIN / 2)) return;
    unsigned n = idx / (DIN / 2);
    unsigned r = idx - n * (DIN / 2);                      // [0, 2*S4)
    bool is_out = (r >= S4);
    unsigned f = is_out ? r - S4 : r;
    const int* row = is_out ? row_out : row_in;
    const int* csr = is_out ? csr_out : csr_in;
    int beg = row[n], end = row[n + 1];
    float invv = 1.0f / fmaxf((float)(end - beg), 1.0f);
    float ax = 0.f, ay = 0.f, az = 0.f, aw = 0.f;
    int j = beg;
    for (; j + 3 < end; j += 4) {                          // 4x16B loads in flight
        int n0 = csr[j], n1 = csr[j + 1], n2 = csr[j + 2], n3 = csr[j + 3];
        float4 v0 = h[(size_t)n0 * S4 + f], v1 = h[(size_t)n1 * S4 + f];
        float4 v2 = h[(size_t)n2 * S4 + f], v3 = h[(size_t)n3 * S4 + f];
        ax += (v0.x + v1.x) + (v2.x + v3.x);
        ay += (v0.y + v1.y) + (v2.y + v3.y);
        az += (v0.z + v1.z) + (v2.z + v3.z);
        aw += (v0.w + v1.w) + (v2.w + v3.w);
    }
    for (; j < end; ++j) {
        float4 v = h[(size_t)csr[j] * S4 + f];
        ax += v.x; ay += v.y; az += v.z; aw += v.w;
    }
    out[(size_t)n * (DIN / 2) + r] = make_float4(ax * invv, ay * invv, az * invv, aw * invv);
}

// ---------- B prep: B[k][j] (256x256) from W[128][512]; j<128 -> Wi, else Wo ----------
__global__ void prep_b_kernel(const float* __restrict__ W, float* __restrict__ B) {
    int idx = blockIdx.x * blockDim.x + threadIdx.x;  // 65536
    int k = idx >> 8, jc = idx & 255;
    B[idx] = (jc < 128) ? W[jc * 512 + k] : W[(jc - 128) * 512 + 256 + k];
}

// ---------- tiled GEMM: C[NN][256] = A[NN][256] * B[256][256] ----------
__global__ void gemm_kernel(const float* __restrict__ A, const float* __restrict__ B,
                            float* __restrict__ C) {
    __shared__ __align__(16) float As[16][68];
    __shared__ __align__(16) float Bs[16][64];
    int tx = threadIdx.x & 15, ty = threadIdx.x >> 4;
    int m0 = blockIdx.x * 64;
    int n0 = blockIdx.y * 64;
    float acc[4][4] = {};
    for (int k0 = 0; k0 < 256; k0 += 16) {
        {
            int r = threadIdx.x >> 2;
            int kq = (threadIdx.x & 3) * 4;
            int m = m0 + r;
            float4 v = (m < NN) ? *(const float4*)&A[(size_t)m * 256 + k0 + kq]
                                : make_float4(0.f, 0.f, 0.f, 0.f);
            As[kq + 0][r] = v.x;
            As[kq + 1][r] = v.y;
            As[kq + 2][r] = v.z;
            As[kq + 3][r] = v.w;
        }
        {
            int kr = threadIdx.x >> 4;
            int nc = (threadIdx.x & 15) * 4;
            *(float4*)&Bs[kr][nc] = *(const float4*)&B[(size_t)(k0 + kr) * 256 + n0 + nc];
        }
        __syncthreads();
#pragma unroll
        for (int k = 0; k < 16; ++k) {
            float4 av = *(const float4*)&As[k][ty * 4];
            float4 bv = *(const float4*)&Bs[k][tx * 4];
            float a[4] = {av.x, av.y, av.z, av.w};
            float bb[4] = {bv.x, bv.y, bv.z, bv.w};
#pragma unroll
            for (int i = 0; i < 4; ++i)
#pragma unroll
                for (int jj = 0; jj < 4; ++jj) acc[i][jj] += a[i] * bb[jj];
        }
        __syncthreads();
    }
#pragma unroll
    for (int i = 0; i < 4; ++i) {
        int m = m0 + ty * 4 + i;
        if (m < NN) {
#pragma unroll
            for (int jj = 0; jj < 4; ++jj)
                C[(size_t)m * 256 + n0 + tx * 4 + jj] = acc[i][jj];
        }
    }
}

// ---------- final hop + bias: float4 lanes; 32 threads per node ----------
__global__ void final_kernel(const float4* __restrict__ g,
                             const int* __restrict__ row_in, const int* __restrict__ csr_in,
                             const int* __restrict__ row_out, const int* __restrict__ csr_out,
                             const float4* __restrict__ b4, float4* __restrict__ out) {
    unsigned idx = blockIdx.x * blockDim.x + threadIdx.x;  // NN * 32
    if (idx >= (unsigned)NN * 32) return;
    unsigned n = idx >> 5, f = idx & 31;
    float ox = 0.f, oy = 0.f, oz = 0.f, ow = 0.f;
    {   // in-direction: g float4 slots [0,32)
        int beg = row_in[n], end = row_in[n + 1];
        float inv = 1.0f / fmaxf((float)(end - beg), 1.0f);
        float sx = 0.f, sy = 0.f, sz = 0.f, sw = 0.f;
        int j = beg;
        for (; j + 3 < end; j += 4) {
            int n0 = csr_in[j], n1 = csr_in[j + 1], n2 = csr_in[j + 2], n3 = csr_in[j + 3];
            float4 v0 = g[(size_t)n0 * 64 + f], v1 = g[(size_t)n1 * 64 + f];
            float4 v2 = g[(size_t)n2 * 64 + f], v3 = g[(size_t)n3 * 64 + f];
            sx += (v0.x + v1.x) + (v2.x + v3.x);
            sy += (v0.y + v1.y) + (v2.y + v3.y);
            sz += (v0.z + v1.z) + (v2.z + v3.z);
            sw += (v0.w + v1.w) + (v2.w + v3.w);
        }
        for (; j < end; ++j) {
            float4 v = g[(size_t)csr_in[j] * 64 + f];
            sx += v.x; sy += v.y; sz += v.z; sw += v.w;
        }
        ox = sx * inv; oy = sy * inv; oz = sz * inv; ow = sw * inv;
    }
    {   // out-direction: g float4 slots [32,64)
        int beg = row_out[n], end = row_out[n + 1];
        float inv = 1.0f / fmaxf((float)(end - beg), 1.0f);
        float sx = 0.f, sy = 0.f, sz = 0.f, sw = 0.f;
        int j = beg;
        for (; j + 3 < end; j += 4) {
            int n0 = csr_out[j], n1 = csr_out[j + 1], n2 = csr_out[j + 2], n3 = csr_out[j + 3];
            float4 v0 = g[(size_t)n0 * 64 + 32 + f], v1 = g[(size_t)n1 * 64 + 32 + f];
            float4 v2 = g[(size_t)n2 * 64 + 32 + f], v3 = g[(size_t)n3 * 64 + 32 + f];
            sx += (v0.x + v1.x) + (v2.x + v3.x);
            sy += (v0.y + v1.y) + (v2.y + v3.y);
            sz += (v0.z + v1.z) + (v2.z + v3.z);
            sw += (v0.w + v1.w) + (v2.w + v3.w);
        }
        for (; j < end; ++j) {
            float4 v = g[(size_t)csr_out[j] * 64 + 32 + f];
            sx += v.x; sy += v.y; sz += v.z; sw += v.w;
        }
        ox += sx * inv; oy += sy * inv; oz += sz * inv; ow += sw * inv;
    }
    float4 bb = b4[f];
    out[(size_t)n * 32 + f] = make_float4(ox + bb.x, oy + bb.y, oz + bb.z, ow + bb.w);
}

extern "C" void kernel_launch(void* const* d_in, const int* in_sizes, int n_in,
                              void* d_out, int out_size, void* d_ws, size_t ws_size,
                              hipStream_t stream) {
    const float* feature = (const float*)d_in[0];
    const int*   edges   = (const int*)d_in[1];   // [2, NE]: src row then dst row
    const float* W       = (const float*)d_in[2];
    const float* b       = (const float*)d_in[3];
    const int* src = edges;
    const int* dst = edges + NE;
    float* out = (float*)d_out;
    float* ws  = (float*)d_ws;

    // Workspace layout; vector-accessed buffers first (16B alignment). ~110 MB total.
    float* h2    = ws;                       // NN*256 floats
    float* g     = h2 + (size_t)NN * 256;    // NN*256 floats
    float* Bmat  = g + (size_t)NN * 256;     // 65536 floats
    int* deg_in  = (int*)(Bmat + 65536);     // NN ints (start of contiguous memset region)
    int* deg_out = deg_in + NN;              // NN ints
    int* cur_in  = deg_out + NN;             // NN ints
    int* cur_out = cur_in + NN;              // NN ints (end of memset region)
    int* row_in  = cur_out + NN;             // NN+1 ints
    int* row_out = row_in + NN + 1;          // NN+1 ints
    int* csr_in  = row_out + NN + 1;         // NE ints
    int* csr_out = csr_in + NE;              // NE ints
    int* partials = csr_out + NE;            // 128 ints
    float* h1 = out;                         // NN*128 lives in d_out; overwritten by final

    (void)hipMemsetAsync(deg_in, 0, (size_t)4 * NN * sizeof(int), stream);
    count_sliced_kernel<<<NSLICE * NCHUNK, 256, 0, stream>>>(src, dst, deg_in, deg_out);
    dim3 sgrid(49, 2);
    scan_block_kernel<<<sgrid, 1024, 0, stream>>>(deg_in, row_in, deg_out, row_out, partials);
    scan_partials_kernel<<<1, 64, 0, stream>>>(partials, row_in, row_out);
    scan_add_kernel<<<sgrid, 1024, 0, stream>>>(row_in, row_out, partials);
    fill_sliced_kernel<<<NSLICE * NCHUNK, 256, 0, stream>>>(src, dst, row_in, row_out,
                                                            cur_in, cur_out, csr_in, csr_out);

    // hop 1: X(64) -> h1(128)
    gather_kernel<64><<<(NN * 32) / 256, 256, 0, stream>>>(
        (const float4*)feature, row_in, csr_in, row_out, csr_out, (float4*)h1);
    // hop 2: h1(128) -> h2(256)
    gather_kernel<128><<<(NN * 64) / 256, 256, 0, stream>>>(
        (const float4*)h1, row_in, csr_in, row_out, csr_out, (float4*)h2);
    // projection folded before hop 3: g = h2 @ [Wi|Wo]^T  (50000x256 @ 256x256)
    prep_b_kernel<<<256, 256, 0, stream>>>(W, Bmat);
    dim3 ggrid((NN + 63) / 64, 4);
    gemm_kernel<<<ggrid, 256, 0, stream>>>(h2, Bmat, g);
    // hop 3 + bias: aggregate g rows -> out
    final_kernel<<<(NN * 32) / 256, 256, 0, stream>>>(
        (const float4*)g, row_in, csr_in, row_out, csr_out, (const float4*)b, (float4*)out);
}

// Round 6
// 398.096 us; speedup vs baseline: 10.8017x; 1.4493x over previous
//
#include <hip/hip_runtime.h>

// LSAGEDirected: 3 directed mean-agg hops (concat in/out) + linear projection.
// R5: bf16 intermediates (h1/h2/g/W) halve all gather traffic; MFMA bf16 GEMM.
// N=50000 nodes, E=800000 edges: 64 ->128 ->256 --MFMA--> 256 --agg--> 128.
#define NN 50000
#define NE 800000
#define NSLICE 8
#define SLICE_N 6250
#define NCHUNK 128
#define CHUNK_E 6250

typedef __attribute__((ext_vector_type(8))) short short8;
typedef __attribute__((ext_vector_type(4))) float floatx4;

// ---- bf16 helpers (ushort storage; manual RNE convert, shift-based upconvert) ----
__device__ __forceinline__ unsigned short f2b(float x) {
    unsigned u = __float_as_uint(x);
    unsigned r = (u + 0x7fffu + ((u >> 16) & 1u)) >> 16;   // round-nearest-even
    return (unsigned short)r;
}
__device__ __forceinline__ unsigned pk2(float lo, float hi) {
    return (unsigned)f2b(lo) | ((unsigned)f2b(hi) << 16);
}
__device__ __forceinline__ float blo(unsigned u) { return __uint_as_float(u << 16); }
__device__ __forceinline__ float bhi(unsigned u) { return __uint_as_float(u & 0xffff0000u); }
__device__ __forceinline__ void acc8(uint4 u, float* a) {
    a[0] += blo(u.x); a[1] += bhi(u.x);
    a[2] += blo(u.y); a[3] += bhi(u.y);
    a[4] += blo(u.z); a[5] += bhi(u.z);
    a[6] += blo(u.w); a[7] += bhi(u.w);
}

// ---------- sliced degree count ----------
__global__ void count_sliced_kernel(const int* __restrict__ src, const int* __restrict__ dst,
                                    int* __restrict__ deg_in, int* __restrict__ deg_out) {
    int slice = blockIdx.x & (NSLICE - 1);
    int chunk = blockIdx.x >> 3;
    int lo = slice * SLICE_N, hi = lo + SLICE_N;
    int e1 = min((chunk + 1) * CHUNK_E, NE);
    for (int e = chunk * CHUNK_E + threadIdx.x; e < e1; e += 256) {
        int s = src[e], d = dst[e];
        if (d >= lo && d < hi) atomicAdd(&deg_in[d], 1);
        if (s >= lo && s < hi) atomicAdd(&deg_out[s], 1);
    }
}

// ---------- 3-phase exclusive scan ----------
__global__ void scan_block_kernel(const int* __restrict__ deg_in, int* __restrict__ row_in,
                                  const int* __restrict__ deg_out, int* __restrict__ row_out,
                                  int* __restrict__ partials) {
    const int* deg = blockIdx.y ? deg_out : deg_in;
    int* row       = blockIdx.y ? row_out : row_in;
    __shared__ int sh[1024];
    int i = blockIdx.x * 1024 + threadIdx.x;
    int v = (i < NN) ? deg[i] : 0;
    sh[threadIdx.x] = v;
    __syncthreads();
    int x = v;
    for (int off = 1; off < 1024; off <<= 1) {
        int y = (threadIdx.x >= off) ? sh[threadIdx.x - off] : 0;
        __syncthreads();
        x += y;
        sh[threadIdx.x] = x;
        __syncthreads();
    }
    if (i < NN) row[i] = x - v;
    if (threadIdx.x == 1023) partials[blockIdx.y * 64 + blockIdx.x] = x;
}

__global__ void scan_partials_kernel(int* __restrict__ partials,
                                     int* __restrict__ row_in, int* __restrict__ row_out) {
    int a = threadIdx.x;
    if (a < 2) {
        int* p = partials + a * 64;
        int run = 0;
        for (int i = 0; i < 49; ++i) { int v = p[i]; p[i] = run; run += v; }
        (a ? row_out : row_in)[NN] = run;
    }
}

__global__ void scan_add_kernel(int* __restrict__ row_in, int* __restrict__ row_out,
                                const int* __restrict__ partials) {
    int i = blockIdx.x * 1024 + threadIdx.x;
    if (i < NN) (blockIdx.y ? row_out : row_in)[i] += partials[blockIdx.y * 64 + blockIdx.x];
}

// ---------- sliced CSR fill ----------
__global__ void fill_sliced_kernel(const int* __restrict__ src, const int* __restrict__ dst,
                                   const int* __restrict__ row_in, const int* __restrict__ row_out,
                                   int* __restrict__ cur_in, int* __restrict__ cur_out,
                                   int* __restrict__ csr_in, int* __restrict__ csr_out) {
    int slice = blockIdx.x & (NSLICE - 1);
    int chunk = blockIdx.x >> 3;
    int lo = slice * SLICE_N, hi = lo + SLICE_N;
    int e1 = min((chunk + 1) * CHUNK_E, NE);
    for (int e = chunk * CHUNK_E + threadIdx.x; e < e1; e += 256) {
        int s = src[e], d = dst[e];
        if (d >= lo && d < hi) csr_in[row_in[d] + atomicAdd(&cur_in[d], 1)] = s;
        if (s >= lo && s < hi) csr_out[row_out[s] + atomicAdd(&cur_out[s], 1)] = d;
    }
}

// ---------- hop 1: feature fp32 [NN][64] -> h1 bf16 [NN][128]; 32 thr/node ----------
__global__ void gather1_kernel(const float4* __restrict__ feat,
                               const int* __restrict__ row_in, const int* __restrict__ csr_in,
                               const int* __restrict__ row_out, const int* __restrict__ csr_out,
                               uint2* __restrict__ h1) {
    unsigned idx = blockIdx.x * 256 + threadIdx.x;   // NN*32 exactly
    unsigned n = idx >> 5, r = idx & 31;             // r: 0-15 in-dir, 16-31 out-dir
    bool is_out = (r >= 16);
    unsigned f = is_out ? r - 16 : r;
    const int* row = is_out ? row_out : row_in;
    const int* csr = is_out ? csr_out : csr_in;
    int beg = row[n], end = row[n + 1];
    float inv = 1.0f / fmaxf((float)(end - beg), 1.0f);
    float ax = 0.f, ay = 0.f, az = 0.f, aw = 0.f;
    int j = beg;
    for (; j + 3 < end; j += 4) {
        int n0 = csr[j], n1 = csr[j + 1], n2 = csr[j + 2], n3 = csr[j + 3];
        float4 v0 = feat[(size_t)n0 * 16 + f], v1 = feat[(size_t)n1 * 16 + f];
        float4 v2 = feat[(size_t)n2 * 16 + f], v3 = feat[(size_t)n3 * 16 + f];
        ax += (v0.x + v1.x) + (v2.x + v3.x);
        ay += (v0.y + v1.y) + (v2.y + v3.y);
        az += (v0.z + v1.z) + (v2.z + v3.z);
        aw += (v0.w + v1.w) + (v2.w + v3.w);
    }
    for (; j < end; ++j) {
        float4 v = feat[(size_t)csr[j] * 16 + f];
        ax += v.x; ay += v.y; az += v.z; aw += v.w;
    }
    // slot r covers bf16 cols 4r..4r+4 of the 128-wide row
    h1[(size_t)n * 32 + r] = make_uint2(pk2(ax * inv, ay * inv), pk2(az * inv, aw * inv));
}

// ---------- hop 2: h1 bf16 [NN][128] -> h2 bf16 [NN][256]; 32 thr/node ----------
__global__ void gather2_kernel(const uint4* __restrict__ h1,
                               const int* __restrict__ row_in, const int* __restrict__ csr_in,
                               const int* __restrict__ row_out, const int* __restrict__ csr_out,
                               uint4* __restrict__ h2) {
    unsigned idx = blockIdx.x * 256 + threadIdx.x;   // NN*32 exactly
    unsigned n = idx >> 5, r = idx & 31;
    bool is_out = (r >= 16);
    unsigned f = is_out ? r - 16 : r;                // uint4 slot within 16-slot h1 row
    const int* row = is_out ? row_out : row_in;
    const int* csr = is_out ? csr_out : csr_in;
    int beg = row[n], end = row[n + 1];
    float inv = 1.0f / fmaxf((float)(end - beg), 1.0f);
    float a[8] = {};
    int j = beg;
    for (; j + 3 < end; j += 4) {
        uint4 u0 = h1[(size_t)csr[j] * 16 + f];
        uint4 u1 = h1[(size_t)csr[j + 1] * 16 + f];
        uint4 u2 = h1[(size_t)csr[j + 2] * 16 + f];
        uint4 u3 = h1[(size_t)csr[j + 3] * 16 + f];
        acc8(u0, a); acc8(u1, a); acc8(u2, a); acc8(u3, a);
    }
    for (; j < end; ++j) acc8(h1[(size_t)csr[j] * 16 + f], a);
    uint4 o;
    o.x = pk2(a[0] * inv, a[1] * inv);
    o.y = pk2(a[2] * inv, a[3] * inv);
    o.z = pk2(a[4] * inv, a[5] * inv);
    o.w = pk2(a[6] * inv, a[7] * inv);
    h2[(size_t)n * 32 + r] = o;   // slot r covers bf16 cols 8r..8r+8 of 256-wide row
}

// ---------- B prep: Bnk bf16 [n][k] 256x256; n<128 -> W[n][k], else W[n-128][256+k] ----------
__global__ void prep_b_kernel(const float* __restrict__ W, unsigned short* __restrict__ Bnk) {
    int idx = blockIdx.x * 256 + threadIdx.x;   // 65536
    int n = idx >> 8, k = idx & 255;
    float v = (n < 128) ? W[n * 512 + k] : W[(n - 128) * 512 + 256 + k];
    Bnk[idx] = f2b(v);
}

// ---------- MFMA GEMM: g[NN][256] bf16 = h2[NN][256] bf16 @ Bnk^T ----------
// block = 256 thr = 4 waves; block computes 64 rows x 256 cols.
// A-frags (all K) in regs; B col-tiles staged in LDS; epilogue via LDS transpose.
__global__ __launch_bounds__(256) void gemm_mfma_kernel(const unsigned short* __restrict__ A,
                                                        const unsigned short* __restrict__ Bnk,
                                                        unsigned short* __restrict__ C) {
    __shared__ unsigned short Bs[16][264];        // 16 n x 256 k, +8 pad (bank spread)
    __shared__ unsigned short Cb[4][16][264];     // per-wave 16x256 strip, +8 pad
    int tid = threadIdx.x;
    int wave = tid >> 6, lane = tid & 63;
    int l15 = lane & 15, q = lane >> 4;
    int m0 = blockIdx.x * 64;
    int mrow = m0 + wave * 16 + l15;
    int mclamp = min(mrow, NN - 1);
    const unsigned short* Arow = A + (size_t)mclamp * 256;
    short8 af[8];
#pragma unroll
    for (int s = 0; s < 8; ++s)
        af[s] = *(const short8*)(Arow + s * 32 + q * 8);   // A[m][k=32s+8q..+8]
    floatx4 acc[16];
#pragma unroll
    for (int c = 0; c < 16; ++c) acc[c] = (floatx4){0.f, 0.f, 0.f, 0.f};
#pragma unroll
    for (int c = 0; c < 16; ++c) {
        {   // stage B rows 16c..16c+16 (each 256 bf16 = 512B); thread t: row t>>4, 32B seg
            int nl = tid >> 4, seg = tid & 15;
            const uint4* srcp = (const uint4*)(Bnk + ((size_t)(16 * c + nl)) * 256 + seg * 16);
            uint4 v0 = srcp[0], v1 = srcp[1];
            *(uint4*)&Bs[nl][seg * 16] = v0;
            *(uint4*)&Bs[nl][seg * 16 + 8] = v1;
        }
        __syncthreads();
#pragma unroll
        for (int s = 0; s < 8; ++s) {
            short8 bf = *(const short8*)&Bs[l15][s * 32 + q * 8];   // B[n=l15][k=32s+8q..+8]
            acc[c] = __builtin_amdgcn_mfma_f32_16x16x32_bf16(af[s], bf, acc[c], 0, 0, 0);
        }
        __syncthreads();
    }
    // epilogue: D lane layout col=l15, row=q*4+reg -> LDS strip -> coalesced stores
#pragma unroll
    for (int c = 0; c < 16; ++c)
#pragma unroll
        for (int r = 0; r < 4; ++r)
            Cb[wave][q * 4 + r][16 * c + l15] = f2b(acc[c][r]);
    __syncthreads();
#pragma unroll
    for (int i = 0; i < 8; ++i) {
        int t = i * 64 + lane;        // 512 uint4 per strip
        int rrow = t >> 5;            // 32 uint4 per 256-bf16 row
        int seg = t & 31;
        int m = m0 + wave * 16 + rrow;
        if (m < NN) {
            uint4 v = *(const uint4*)&Cb[wave][rrow][seg * 8];
            *(uint4*)(C + (size_t)m * 256 + seg * 8) = v;
        }
    }
}

// ---------- final hop + bias: gather g bf16, both directions sum; 16 thr/node ----------
__global__ void final_kernel(const uint4* __restrict__ g,
                             const int* __restrict__ row_in, const int* __restrict__ csr_in,
                             const int* __restrict__ row_out, const int* __restrict__ csr_out,
                             const float4* __restrict__ b4, float4* __restrict__ out) {
    unsigned idx = blockIdx.x * 256 + threadIdx.x;   // NN*16 exactly
    unsigned n = idx >> 4, f = idx & 15;             // f: uint4 slot -> out cols 8f..8f+8
    float a[8] = {};
    {   // in-direction: g slots [0,16)
        int beg = row_in[n], end = row_in[n + 1];
        float inv = 1.0f / fmaxf((float)(end - beg), 1.0f);
        float s[8] = {};
        int j = beg;
        for (; j + 3 < end; j += 4) {
            uint4 u0 = g[(size_t)csr_in[j] * 32 + f];
            uint4 u1 = g[(size_t)csr_in[j + 1] * 32 + f];
            uint4 u2 = g[(size_t)csr_in[j + 2] * 32 + f];
            uint4 u3 = g[(size_t)csr_in[j + 3] * 32 + f];
            acc8(u0, s); acc8(u1, s); acc8(u2, s); acc8(u3, s);
        }
        for (; j < end; ++j) acc8(g[(size_t)csr_in[j] * 32 + f], s);
#pragma unroll
        for (int i = 0; i < 8; ++i) a[i] += s[i] * inv;
    }
    {   // out-direction: g slots [16,32)
        int beg = row_out[n], end = row_out[n + 1];
        float inv = 1.0f / fmaxf((float)(end - beg), 1.0f);
        float s[8] = {};
        int j = beg;
        for (; j + 3 < end; j += 4) {
            uint4 u0 = g[(size_t)csr_out[j] * 32 + 16 + f];
            uint4 u1 = g[(size_t)csr_out[j + 1] * 32 + 16 + f];
            uint4 u2 = g[(size_t)csr_out[j + 2] * 32 + 16 + f];
            uint4 u3 = g[(size_t)csr_out[j + 3] * 32 + 16 + f];
            acc8(u0, s); acc8(u1, s); acc8(u2, s); acc8(u3, s);
        }
        for (; j < end; ++j) acc8(g[(size_t)csr_out[j] * 32 + 16 + f], s);
#pragma unroll
        for (int i = 0; i < 8; ++i) a[i] += s[i] * inv;
    }
    float4 b0 = b4[2 * f], b1 = b4[2 * f + 1];
    out[(size_t)n * 32 + 2 * f]     = make_float4(a[0] + b0.x, a[1] + b0.y, a[2] + b0.z, a[3] + b0.w);
    out[(size_t)n * 32 + 2 * f + 1] = make_float4(a[4] + b1.x, a[5] + b1.y, a[6] + b1.z, a[7] + b1.w);
}

extern "C" void kernel_launch(void* const* d_in, const int* in_sizes, int n_in,
                              void* d_out, int out_size, void* d_ws, size_t ws_size,
                              hipStream_t stream) {
    const float* feature = (const float*)d_in[0];
    const int*   edges   = (const int*)d_in[1];   // [2, NE]: src row then dst row
    const float* W       = (const float*)d_in[2];
    const float* b       = (const float*)d_in[3];
    const int* src = edges;
    const int* dst = edges + NE;
    float* out = (float*)d_out;

    // Workspace layout (16B-aligned chunks). ~71 MB total.
    unsigned short* h1b = (unsigned short*)d_ws;        // NN*128 bf16
    unsigned short* h2b = h1b + (size_t)NN * 128;       // NN*256 bf16
    unsigned short* gb  = h2b + (size_t)NN * 256;       // NN*256 bf16
    unsigned short* Bnk = gb + (size_t)NN * 256;        // 65536 bf16
    int* deg_in  = (int*)(Bnk + 65536);                 // NN ints (memset region start)
    int* deg_out = deg_in + NN;
    int* cur_in  = deg_out + NN;
    int* cur_out = cur_in + NN;                          // memset region end
    int* row_in  = cur_out + NN;                         // NN+1
    int* row_out = row_in + NN + 1;                      // NN+1
    int* csr_in  = row_out + NN + 1;                     // NE
    int* csr_out = csr_in + NE;                          // NE
    int* partials = csr_out + NE;                        // 128

    (void)hipMemsetAsync(deg_in, 0, (size_t)4 * NN * sizeof(int), stream);
    count_sliced_kernel<<<NSLICE * NCHUNK, 256, 0, stream>>>(src, dst, deg_in, deg_out);
    dim3 sgrid(49, 2);
    scan_block_kernel<<<sgrid, 1024, 0, stream>>>(deg_in, row_in, deg_out, row_out, partials);
    scan_partials_kernel<<<1, 64, 0, stream>>>(partials, row_in, row_out);
    scan_add_kernel<<<sgrid, 1024, 0, stream>>>(row_in, row_out, partials);
    fill_sliced_kernel<<<NSLICE * NCHUNK, 256, 0, stream>>>(src, dst, row_in, row_out,
                                                            cur_in, cur_out, csr_in, csr_out);
    prep_b_kernel<<<256, 256, 0, stream>>>(W, Bnk);

    // hop 1: feature(64 fp32) -> h1(128 bf16)
    gather1_kernel<<<(NN * 32) / 256, 256, 0, stream>>>(
        (const float4*)feature, row_in, csr_in, row_out, csr_out, (uint2*)h1b);
    // hop 2: h1(128 bf16) -> h2(256 bf16)
    gather2_kernel<<<(NN * 32) / 256, 256, 0, stream>>>(
        (const uint4*)h1b, row_in, csr_in, row_out, csr_out, (uint4*)h2b);
    // projection (folded before hop 3): g = h2 @ Bnk^T via bf16 MFMA
    gemm_mfma_kernel<<<(NN + 63) / 64, 256, 0, stream>>>(h2b, Bnk, gb);
    // hop 3 + bias: aggregate g rows -> out (fp32)
    final_kernel<<<(NN * 16) / 256, 256, 0, stream>>>(
        (const uint4*)gb, row_in, csr_in, row_out, csr_out, (const float4*)b, (float4*)out);
}

// Round 7
// 312.764 us; speedup vs baseline: 13.7487x; 1.2728x over previous
//
#include <hip/hip_runtime.h>

// LSAGEDirected: 3 directed mean-agg hops (concat in/out) + linear projection.
// R6: bucket+LDS-counting-sort CSR build (no write amplification), bf16 feature,
//     bf16 intermediates, MFMA bf16 GEMM (W folded before hop 3).
// N=50000 nodes, E=800000 edges: 64 ->128 ->256 --MFMA--> 256 --agg--> 128.
#define NN 50000
#define NE 800000
#define NBUCK 100
#define BUCK_N 500        // NN / NBUCK
#define CAP 10016         // per-bucket pair capacity (avg 8000, 22-sigma safe)
#define PA_BLOCKS 64
#define PA_CHUNK (NE / PA_BLOCKS)   // 12500

typedef __attribute__((ext_vector_type(8))) short short8;
typedef __attribute__((ext_vector_type(4))) float floatx4;

// ---- bf16 helpers (ushort storage; RNE convert, shift-based upconvert) ----
__device__ __forceinline__ unsigned short f2b(float x) {
    unsigned u = __float_as_uint(x);
    return (unsigned short)((u + 0x7fffu + ((u >> 16) & 1u)) >> 16);
}
__device__ __forceinline__ unsigned pk2(float lo, float hi) {
    return (unsigned)f2b(lo) | ((unsigned)f2b(hi) << 16);
}
__device__ __forceinline__ float blo(unsigned u) { return __uint_as_float(u << 16); }
__device__ __forceinline__ float bhi(unsigned u) { return __uint_as_float(u & 0xffff0000u); }
__device__ __forceinline__ void acc8(uint4 u, float* a) {
    a[0] += blo(u.x); a[1] += bhi(u.x);
    a[2] += blo(u.y); a[3] += bhi(u.y);
    a[4] += blo(u.z); a[5] += bhi(u.z);
    a[6] += blo(u.w); a[7] += bhi(u.w);
}

// ---------- feature fp32 -> bf16 ----------
__global__ void featb_kernel(const float4* __restrict__ f32, uint2* __restrict__ fb) {
    int idx = blockIdx.x * 256 + threadIdx.x;   // NN*16 exactly
    float4 v = f32[idx];
    fb[idx] = make_uint2(pk2(v.x, v.y), pk2(v.z, v.w));
}

// ---------- Phase A: bucket edges by dst (in-dir) and src (out-dir) ----------
// Per (block,bucket) reservation -> contiguous ~1KB pair runs (full-line writes).
__global__ __launch_bounds__(256) void bucket_kernel(const int* __restrict__ src,
                                                     const int* __restrict__ dst,
                                                     int* __restrict__ gcnt_in,
                                                     int* __restrict__ gcnt_out,
                                                     int2* __restrict__ pin,
                                                     int2* __restrict__ pout) {
    __shared__ int cin[NBUCK], cout[NBUCK], rin[NBUCK], rout[NBUCK];
    int tid = threadIdx.x;
    for (int t = tid; t < NBUCK; t += 256) { cin[t] = 0; cout[t] = 0; }
    __syncthreads();
    int e0 = blockIdx.x * PA_CHUNK, e1 = e0 + PA_CHUNK;
    for (int e = e0 + tid; e < e1; e += 256) {
        atomicAdd(&cin[dst[e] / BUCK_N], 1);
        atomicAdd(&cout[src[e] / BUCK_N], 1);
    }
    __syncthreads();
    for (int t = tid; t < NBUCK; t += 256) {
        rin[t]  = atomicAdd(&gcnt_in[t], cin[t]);
        rout[t] = atomicAdd(&gcnt_out[t], cout[t]);
        cin[t] = 0; cout[t] = 0;
    }
    __syncthreads();
    for (int e = e0 + tid; e < e1; e += 256) {
        int s = src[e], d = dst[e];
        int bi = d / BUCK_N;
        int p = atomicAdd(&cin[bi], 1);
        pin[(size_t)bi * CAP + rin[bi] + p] = make_int2(d, s);
        int bo = s / BUCK_N;
        int q = atomicAdd(&cout[bo], 1);
        pout[(size_t)bo * CAP + rout[bo] + q] = make_int2(s, d);
    }
}

// ---------- tiny scan of 100 bucket counts per direction ----------
__global__ void bucket_scan_kernel(const int* __restrict__ gcnt_in,
                                   const int* __restrict__ gcnt_out,
                                   int* __restrict__ bb_in, int* __restrict__ bb_out) {
    if (threadIdx.x == 0) {
        int run = 0;
        for (int b = 0; b < NBUCK; ++b) { bb_in[b] = run; run += gcnt_in[b]; }
    }
    if (threadIdx.x == 1) {
        int run = 0;
        for (int b = 0; b < NBUCK; ++b) { bb_out[b] = run; run += gcnt_out[b]; }
    }
}

// ---------- Phase B: per-(bucket,dir) CSR via LDS counting sort ----------
// One block; deg/scan/cursors in LDS; row+csr writes are block-local contiguous.
__global__ __launch_bounds__(1024) void csr_build_kernel(const int2* __restrict__ pin,
                                                         const int2* __restrict__ pout,
                                                         const int* __restrict__ gcnt_in,
                                                         const int* __restrict__ gcnt_out,
                                                         const int* __restrict__ bb_in,
                                                         const int* __restrict__ bb_out,
                                                         int* __restrict__ row_in,
                                                         int* __restrict__ row_out,
                                                         int* __restrict__ csr_in,
                                                         int* __restrict__ csr_out) {
    bool dirout = blockIdx.x >= NBUCK;
    int b = dirout ? blockIdx.x - NBUCK : blockIdx.x;
    const int2* pairs = (dirout ? pout : pin) + (size_t)b * CAP;
    int cnt  = dirout ? gcnt_out[b] : gcnt_in[b];
    int base = dirout ? bb_out[b] : bb_in[b];
    int* row = dirout ? row_out : row_in;
    int* csr = dirout ? csr_out : csr_in;
    int lo = b * BUCK_N;
    __shared__ int deg[BUCK_N], incl[BUCK_N], cur[BUCK_N];
    int tid = threadIdx.x;
    for (int t = tid; t < BUCK_N; t += 1024) { deg[t] = 0; cur[t] = 0; }
    __syncthreads();
    for (int i = tid; i < cnt; i += 1024) atomicAdd(&deg[pairs[i].x - lo], 1);
    __syncthreads();
    if (tid < BUCK_N) incl[tid] = deg[tid];
    __syncthreads();
    for (int off = 1; off < BUCK_N; off <<= 1) {
        int v = 0;
        if (tid < BUCK_N && tid >= off) v = incl[tid - off];
        __syncthreads();
        if (tid < BUCK_N) incl[tid] += v;
        __syncthreads();
    }
    if (tid < BUCK_N) row[lo + tid] = base + incl[tid] - deg[tid];
    if (tid == 0 && b == NBUCK - 1) row[NN] = base + incl[BUCK_N - 1];
    __syncthreads();
    for (int i = tid; i < cnt; i += 1024) {
        int2 pr = pairs[i];
        int li = pr.x - lo;
        int pos = atomicAdd(&cur[li], 1);
        csr[base + incl[li] - deg[li] + pos] = pr.y;
    }
}

// ---------- hop 1: featb bf16 [NN][64] -> h1 bf16 [NN][128]; 32 thr/node ----------
__global__ void gather1_kernel(const uint2* __restrict__ feat,
                               const int* __restrict__ row_in, const int* __restrict__ csr_in,
                               const int* __restrict__ row_out, const int* __restrict__ csr_out,
                               uint2* __restrict__ h1) {
    unsigned idx = blockIdx.x * 256 + threadIdx.x;   // NN*32 exactly
    unsigned n = idx >> 5, r = idx & 31;             // r: 0-15 in-dir, 16-31 out-dir
    bool is_out = (r >= 16);
    unsigned f = is_out ? r - 16 : r;                // uint2 slot (4 bf16 cols) of featb row
    const int* row = is_out ? row_out : row_in;
    const int* csr = is_out ? csr_out : csr_in;
    int beg = row[n], end = row[n + 1];
    float inv = 1.0f / fmaxf((float)(end - beg), 1.0f);
    float a0 = 0.f, a1 = 0.f, a2 = 0.f, a3 = 0.f;
    int j = beg;
    for (; j + 3 < end; j += 4) {
        uint2 u0 = feat[(size_t)csr[j] * 16 + f];
        uint2 u1 = feat[(size_t)csr[j + 1] * 16 + f];
        uint2 u2 = feat[(size_t)csr[j + 2] * 16 + f];
        uint2 u3 = feat[(size_t)csr[j + 3] * 16 + f];
        a0 += (blo(u0.x) + blo(u1.x)) + (blo(u2.x) + blo(u3.x));
        a1 += (bhi(u0.x) + bhi(u1.x)) + (bhi(u2.x) + bhi(u3.x));
        a2 += (blo(u0.y) + blo(u1.y)) + (blo(u2.y) + blo(u3.y));
        a3 += (bhi(u0.y) + bhi(u1.y)) + (bhi(u2.y) + bhi(u3.y));
    }
    for (; j < end; ++j) {
        uint2 u = feat[(size_t)csr[j] * 16 + f];
        a0 += blo(u.x); a1 += bhi(u.x); a2 += blo(u.y); a3 += bhi(u.y);
    }
    h1[(size_t)n * 32 + r] = make_uint2(pk2(a0 * inv, a1 * inv), pk2(a2 * inv, a3 * inv));
}

// ---------- hop 2: h1 bf16 [NN][128] -> h2 bf16 [NN][256]; 32 thr/node ----------
__global__ void gather2_kernel(const uint4* __restrict__ h1,
                               const int* __restrict__ row_in, const int* __restrict__ csr_in,
                               const int* __restrict__ row_out, const int* __restrict__ csr_out,
                               uint4* __restrict__ h2) {
    unsigned idx = blockIdx.x * 256 + threadIdx.x;   // NN*32 exactly
    unsigned n = idx >> 5, r = idx & 31;
    bool is_out = (r >= 16);
    unsigned f = is_out ? r - 16 : r;                // uint4 slot within 16-slot h1 row
    const int* row = is_out ? row_out : row_in;
    const int* csr = is_out ? csr_out : csr_in;
    int beg = row[n], end = row[n + 1];
    float inv = 1.0f / fmaxf((float)(end - beg), 1.0f);
    float a[8] = {};
    int j = beg;
    for (; j + 3 < end; j += 4) {
        uint4 u0 = h1[(size_t)csr[j] * 16 + f];
        uint4 u1 = h1[(size_t)csr[j + 1] * 16 + f];
        uint4 u2 = h1[(size_t)csr[j + 2] * 16 + f];
        uint4 u3 = h1[(size_t)csr[j + 3] * 16 + f];
        acc8(u0, a); acc8(u1, a); acc8(u2, a); acc8(u3, a);
    }
    for (; j < end; ++j) acc8(h1[(size_t)csr[j] * 16 + f], a);
    uint4 o;
    o.x = pk2(a[0] * inv, a[1] * inv);
    o.y = pk2(a[2] * inv, a[3] * inv);
    o.z = pk2(a[4] * inv, a[5] * inv);
    o.w = pk2(a[6] * inv, a[7] * inv);
    h2[(size_t)n * 32 + r] = o;
}

// ---------- B prep: Bnk bf16 [n][k] 256x256; n<128 -> W[n][k], else W[n-128][256+k] ----------
__global__ void prep_b_kernel(const float* __restrict__ W, unsigned short* __restrict__ Bnk) {
    int idx = blockIdx.x * 256 + threadIdx.x;   // 65536
    int n = idx >> 8, k = idx & 255;
    float v = (n < 128) ? W[n * 512 + k] : W[(n - 128) * 512 + 256 + k];
    Bnk[idx] = f2b(v);
}

// ---------- MFMA GEMM: g[NN][256] bf16 = h2[NN][256] bf16 @ Bnk^T ----------
__global__ __launch_bounds__(256) void gemm_mfma_kernel(const unsigned short* __restrict__ A,
                                                        const unsigned short* __restrict__ Bnk,
                                                        unsigned short* __restrict__ C) {
    __shared__ unsigned short Bs[16][264];
    __shared__ unsigned short Cb[4][16][264];
    int tid = threadIdx.x;
    int wave = tid >> 6, lane = tid & 63;
    int l15 = lane & 15, q = lane >> 4;
    int m0 = blockIdx.x * 64;
    int mrow = m0 + wave * 16 + l15;
    int mclamp = min(mrow, NN - 1);
    const unsigned short* Arow = A + (size_t)mclamp * 256;
    short8 af[8];
#pragma unroll
    for (int s = 0; s < 8; ++s)
        af[s] = *(const short8*)(Arow + s * 32 + q * 8);
    floatx4 acc[16];
#pragma unroll
    for (int c = 0; c < 16; ++c) acc[c] = (floatx4){0.f, 0.f, 0.f, 0.f};
#pragma unroll
    for (int c = 0; c < 16; ++c) {
        {
            int nl = tid >> 4, seg = tid & 15;
            const uint4* srcp = (const uint4*)(Bnk + ((size_t)(16 * c + nl)) * 256 + seg * 16);
            uint4 v0 = srcp[0], v1 = srcp[1];
            *(uint4*)&Bs[nl][seg * 16] = v0;
            *(uint4*)&Bs[nl][seg * 16 + 8] = v1;
        }
        __syncthreads();
#pragma unroll
        for (int s = 0; s < 8; ++s) {
            short8 bf = *(const short8*)&Bs[l15][s * 32 + q * 8];
            acc[c] = __builtin_amdgcn_mfma_f32_16x16x32_bf16(af[s], bf, acc[c], 0, 0, 0);
        }
        __syncthreads();
    }
#pragma unroll
    for (int c = 0; c < 16; ++c)
#pragma unroll
        for (int r = 0; r < 4; ++r)
            Cb[wave][q * 4 + r][16 * c + l15] = f2b(acc[c][r]);
    __syncthreads();
#pragma unroll
    for (int i = 0; i < 8; ++i) {
        int t = i * 64 + lane;
        int rrow = t >> 5;
        int seg = t & 31;
        int m = m0 + wave * 16 + rrow;
        if (m < NN) {
            uint4 v = *(const uint4*)&Cb[wave][rrow][seg * 8];
            *(uint4*)(C + (size_t)m * 256 + seg * 8) = v;
        }
    }
}

// ---------- final hop + bias: gather g bf16, both directions; 16 thr/node ----------
__global__ void final_kernel(const uint4* __restrict__ g,
                             const int* __restrict__ row_in, const int* __restrict__ csr_in,
                             const int* __restrict__ row_out, const int* __restrict__ csr_out,
                             const float4* __restrict__ b4, float4* __restrict__ out) {
    unsigned idx = blockIdx.x * 256 + threadIdx.x;   // NN*16 exactly
    unsigned n = idx >> 4, f = idx & 15;
    float a[8] = {};
    {
        int beg = row_in[n], end = row_in[n + 1];
        float inv = 1.0f / fmaxf((float)(end - beg), 1.0f);
        float s[8] = {};
        int j = beg;
        for (; j + 3 < end; j += 4) {
            uint4 u0 = g[(size_t)csr_in[j] * 32 + f];
            uint4 u1 = g[(size_t)csr_in[j + 1] * 32 + f];
            uint4 u2 = g[(size_t)csr_in[j + 2] * 32 + f];
            uint4 u3 = g[(size_t)csr_in[j + 3] * 32 + f];
            acc8(u0, s); acc8(u1, s); acc8(u2, s); acc8(u3, s);
        }
        for (; j < end; ++j) acc8(g[(size_t)csr_in[j] * 32 + f], s);
#pragma unroll
        for (int i = 0; i < 8; ++i) a[i] += s[i] * inv;
    }
    {
        int beg = row_out[n], end = row_out[n + 1];
        float inv = 1.0f / fmaxf((float)(end - beg), 1.0f);
        float s[8] = {};
        int j = beg;
        for (; j + 3 < end; j += 4) {
            uint4 u0 = g[(size_t)csr_out[j] * 32 + 16 + f];
            uint4 u1 = g[(size_t)csr_out[j + 1] * 32 + 16 + f];
            uint4 u2 = g[(size_t)csr_out[j + 2] * 32 + 16 + f];
            uint4 u3 = g[(size_t)csr_out[j + 3] * 32 + 16 + f];
            acc8(u0, s); acc8(u1, s); acc8(u2, s); acc8(u3, s);
        }
        for (; j < end; ++j) acc8(g[(size_t)csr_out[j] * 32 + 16 + f], s);
#pragma unroll
        for (int i = 0; i < 8; ++i) a[i] += s[i] * inv;
    }
    float4 b0 = b4[2 * f], b1 = b4[2 * f + 1];
    out[(size_t)n * 32 + 2 * f]     = make_float4(a[0] + b0.x, a[1] + b0.y, a[2] + b0.z, a[3] + b0.w);
    out[(size_t)n * 32 + 2 * f + 1] = make_float4(a[4] + b1.x, a[5] + b1.y, a[6] + b1.z, a[7] + b1.w);
}

extern "C" void kernel_launch(void* const* d_in, const int* in_sizes, int n_in,
                              void* d_out, int out_size, void* d_ws, size_t ws_size,
                              hipStream_t stream) {
    const float* feature = (const float*)d_in[0];
    const int*   edges   = (const int*)d_in[1];   // [2, NE]: src row then dst row
    const float* W       = (const float*)d_in[2];
    const float* b       = (const float*)d_in[3];
    const int* src = edges;
    const int* dst = edges + NE;
    float* out = (float*)d_out;

    // Workspace layout (16B-aligned chunks first). ~94 MB total.
    unsigned short* featb = (unsigned short*)d_ws;       // NN*64 bf16
    unsigned short* h1b = featb + (size_t)NN * 64;       // NN*128 bf16
    unsigned short* h2b = h1b + (size_t)NN * 128;        // NN*256 bf16
    unsigned short* gb  = h2b + (size_t)NN * 256;        // NN*256 bf16
    unsigned short* Bnk = gb + (size_t)NN * 256;         // 65536 bf16
    int2* pin  = (int2*)(Bnk + 65536);                   // NBUCK*CAP pairs
    int2* pout = pin + (size_t)NBUCK * CAP;              // NBUCK*CAP pairs
    int* csr_in  = (int*)(pout + (size_t)NBUCK * CAP);   // NE
    int* csr_out = csr_in + NE;                          // NE
    int* row_in  = csr_out + NE;                         // NN+1
    int* row_out = row_in + NN + 1;                      // NN+1
    int* gcnt_in  = row_out + NN + 1;                    // 128 (memset region start)
    int* gcnt_out = gcnt_in + 128;                       // 128 (memset region end)
    int* bb_in   = gcnt_out + 128;                       // 128
    int* bb_out  = bb_in + 128;                          // 128

    (void)hipMemsetAsync(gcnt_in, 0, 256 * sizeof(int), stream);
    featb_kernel<<<(NN * 16) / 256, 256, 0, stream>>>((const float4*)feature, (uint2*)featb);
    prep_b_kernel<<<256, 256, 0, stream>>>(W, Bnk);
    bucket_kernel<<<PA_BLOCKS, 256, 0, stream>>>(src, dst, gcnt_in, gcnt_out, pin, pout);
    bucket_scan_kernel<<<1, 64, 0, stream>>>(gcnt_in, gcnt_out, bb_in, bb_out);
    csr_build_kernel<<<2 * NBUCK, 1024, 0, stream>>>(pin, pout, gcnt_in, gcnt_out,
                                                     bb_in, bb_out, row_in, row_out,
                                                     csr_in, csr_out);

    // hop 1: featb(64 bf16) -> h1(128 bf16)
    gather1_kernel<<<(NN * 32) / 256, 256, 0, stream>>>(
        (const uint2*)featb, row_in, csr_in, row_out, csr_out, (uint2*)h1b);
    // hop 2: h1(128 bf16) -> h2(256 bf16)
    gather2_kernel<<<(NN * 32) / 256, 256, 0, stream>>>(
        (const uint4*)h1b, row_in, csr_in, row_out, csr_out, (uint4*)h2b);
    // projection (folded before hop 3): g = h2 @ Bnk^T via bf16 MFMA
    gemm_mfma_kernel<<<(NN + 63) / 64, 256, 0, stream>>>(h2b, Bnk, gb);
    // hop 3 + bias: aggregate g rows -> out (fp32)
    final_kernel<<<(NN * 16) / 256, 256, 0, stream>>>(
        (const uint4*)gb, row_in, csr_in, row_out, csr_out, (const float4*)b, (float4*)out);
}

// Round 8
// 309.029 us; speedup vs baseline: 13.9149x; 1.0121x over previous
//
#include <hip/hip_runtime.h>

// LSAGEDirected: 3 directed mean-agg hops (concat in/out) + linear projection.
// R7: bucket build at 500 blocks (was 64 — 2.5% occupancy), uint4 gather1,
//     unroll-8 gather loops. bf16 intermediates + MFMA GEMM as R6.
// N=50000 nodes, E=800000 edges: 64 ->128 ->256 --MFMA--> 256 --agg--> 128.
#define NN 50000
#define NE 800000
#define NBUCK 100
#define BUCK_N 500        // NN / NBUCK
#define CAP 10016         // per-bucket pair capacity (avg 8000)
#define PA_BLOCKS 500
#define PA_CHUNK 1600     // NE / PA_BLOCKS

typedef __attribute__((ext_vector_type(8))) short short8;
typedef __attribute__((ext_vector_type(4))) float floatx4;

// ---- bf16 helpers (ushort storage; RNE convert, shift-based upconvert) ----
__device__ __forceinline__ unsigned short f2b(float x) {
    unsigned u = __float_as_uint(x);
    return (unsigned short)((u + 0x7fffu + ((u >> 16) & 1u)) >> 16);
}
__device__ __forceinline__ unsigned pk2(float lo, float hi) {
    return (unsigned)f2b(lo) | ((unsigned)f2b(hi) << 16);
}
__device__ __forceinline__ float blo(unsigned u) { return __uint_as_float(u << 16); }
__device__ __forceinline__ float bhi(unsigned u) { return __uint_as_float(u & 0xffff0000u); }
__device__ __forceinline__ void acc8(uint4 u, float* a) {
    a[0] += blo(u.x); a[1] += bhi(u.x);
    a[2] += blo(u.y); a[3] += bhi(u.y);
    a[4] += blo(u.z); a[5] += bhi(u.z);
    a[6] += blo(u.w); a[7] += bhi(u.w);
}

// ---------- feature fp32 -> bf16 ----------
__global__ void featb_kernel(const float4* __restrict__ f32, uint2* __restrict__ fb) {
    int idx = blockIdx.x * 256 + threadIdx.x;   // NN*16 exactly
    float4 v = f32[idx];
    fb[idx] = make_uint2(pk2(v.x, v.y), pk2(v.z, v.w));
}

// ---------- Phase A: bucket edges by dst (in-dir) and src (out-dir) ----------
__global__ __launch_bounds__(256) void bucket_kernel(const int* __restrict__ src,
                                                     const int* __restrict__ dst,
                                                     int* __restrict__ gcnt_in,
                                                     int* __restrict__ gcnt_out,
                                                     int2* __restrict__ pin,
                                                     int2* __restrict__ pout) {
    __shared__ int cin[NBUCK], cout[NBUCK], rin[NBUCK], rout[NBUCK];
    int tid = threadIdx.x;
    if (tid < NBUCK) { cin[tid] = 0; cout[tid] = 0; }
    __syncthreads();
    int e0 = blockIdx.x * PA_CHUNK, e1 = e0 + PA_CHUNK;
    for (int e = e0 + tid; e < e1; e += 256) {
        atomicAdd(&cin[dst[e] / BUCK_N], 1);
        atomicAdd(&cout[src[e] / BUCK_N], 1);
    }
    __syncthreads();
    if (tid < NBUCK) {
        rin[tid]  = atomicAdd(&gcnt_in[tid], cin[tid]);
        rout[tid] = atomicAdd(&gcnt_out[tid], cout[tid]);
        cin[tid] = 0; cout[tid] = 0;
    }
    __syncthreads();
    for (int e = e0 + tid; e < e1; e += 256) {
        int s = src[e], d = dst[e];
        int bi = d / BUCK_N;
        int p = atomicAdd(&cin[bi], 1);
        pin[(size_t)bi * CAP + rin[bi] + p] = make_int2(d, s);
        int bo = s / BUCK_N;
        int q = atomicAdd(&cout[bo], 1);
        pout[(size_t)bo * CAP + rout[bo] + q] = make_int2(s, d);
    }
}

// ---------- tiny scan of 100 bucket counts per direction ----------
__global__ void bucket_scan_kernel(const int* __restrict__ gcnt_in,
                                   const int* __restrict__ gcnt_out,
                                   int* __restrict__ bb_in, int* __restrict__ bb_out) {
    if (threadIdx.x == 0) {
        int run = 0;
        for (int b = 0; b < NBUCK; ++b) { bb_in[b] = run; run += gcnt_in[b]; }
    }
    if (threadIdx.x == 1) {
        int run = 0;
        for (int b = 0; b < NBUCK; ++b) { bb_out[b] = run; run += gcnt_out[b]; }
    }
}

// ---------- Phase B: per-(bucket,dir) CSR via LDS counting sort ----------
__global__ __launch_bounds__(1024) void csr_build_kernel(const int2* __restrict__ pin,
                                                         const int2* __restrict__ pout,
                                                         const int* __restrict__ gcnt_in,
                                                         const int* __restrict__ gcnt_out,
                                                         const int* __restrict__ bb_in,
                                                         const int* __restrict__ bb_out,
                                                         int* __restrict__ row_in,
                                                         int* __restrict__ row_out,
                                                         int* __restrict__ csr_in,
                                                         int* __restrict__ csr_out) {
    bool dirout = blockIdx.x >= NBUCK;
    int b = dirout ? blockIdx.x - NBUCK : blockIdx.x;
    const int2* pairs = (dirout ? pout : pin) + (size_t)b * CAP;
    int cnt  = dirout ? gcnt_out[b] : gcnt_in[b];
    int base = dirout ? bb_out[b] : bb_in[b];
    int* row = dirout ? row_out : row_in;
    int* csr = dirout ? csr_out : csr_in;
    int lo = b * BUCK_N;
    __shared__ int deg[BUCK_N], incl[BUCK_N], cur[BUCK_N];
    int tid = threadIdx.x;
    if (tid < BUCK_N) { deg[tid] = 0; cur[tid] = 0; }
    __syncthreads();
    for (int i = tid; i < cnt; i += 1024) atomicAdd(&deg[pairs[i].x - lo], 1);
    __syncthreads();
    if (tid < BUCK_N) incl[tid] = deg[tid];
    __syncthreads();
    for (int off = 1; off < BUCK_N; off <<= 1) {
        int v = 0;
        if (tid < BUCK_N && tid >= off) v = incl[tid - off];
        __syncthreads();
        if (tid < BUCK_N) incl[tid] += v;
        __syncthreads();
    }
    if (tid < BUCK_N) row[lo + tid] = base + incl[tid] - deg[tid];
    if (tid == 0 && b == NBUCK - 1) row[NN] = base + incl[BUCK_N - 1];
    __syncthreads();
    for (int i = tid; i < cnt; i += 1024) {
        int2 pr = pairs[i];
        int li = pr.x - lo;
        int pos = atomicAdd(&cur[li], 1);
        csr[base + incl[li] - deg[li] + pos] = pr.y;
    }
}

// ---------- hop 1: featb bf16 [NN][64] -> h1 bf16 [NN][128]; 16 thr/node, uint4 ----------
__global__ void gather1_kernel(const uint4* __restrict__ feat,
                               const int* __restrict__ row_in, const int* __restrict__ csr_in,
                               const int* __restrict__ row_out, const int* __restrict__ csr_out,
                               uint4* __restrict__ h1) {
    unsigned idx = blockIdx.x * 256 + threadIdx.x;   // NN*16 exactly
    unsigned n = idx >> 4, r = idx & 15;             // r: 0-7 in-dir, 8-15 out-dir
    bool is_out = (r >= 8);
    unsigned f = r & 7;                              // uint4 slot (8 bf16 cols) of featb row
    const int* row = is_out ? row_out : row_in;
    const int* csr = is_out ? csr_out : csr_in;
    int beg = row[n], end = row[n + 1];
    float inv = 1.0f / fmaxf((float)(end - beg), 1.0f);
    float a[8] = {};
    int j = beg;
    for (; j + 7 < end; j += 8) {
        uint4 u0 = feat[(size_t)csr[j] * 8 + f];
        uint4 u1 = feat[(size_t)csr[j + 1] * 8 + f];
        uint4 u2 = feat[(size_t)csr[j + 2] * 8 + f];
        uint4 u3 = feat[(size_t)csr[j + 3] * 8 + f];
        uint4 u4 = feat[(size_t)csr[j + 4] * 8 + f];
        uint4 u5 = feat[(size_t)csr[j + 5] * 8 + f];
        uint4 u6 = feat[(size_t)csr[j + 6] * 8 + f];
        uint4 u7 = feat[(size_t)csr[j + 7] * 8 + f];
        acc8(u0, a); acc8(u1, a); acc8(u2, a); acc8(u3, a);
        acc8(u4, a); acc8(u5, a); acc8(u6, a); acc8(u7, a);
    }
    for (; j < end; ++j) acc8(feat[(size_t)csr[j] * 8 + f], a);
    uint4 o;
    o.x = pk2(a[0] * inv, a[1] * inv);
    o.y = pk2(a[2] * inv, a[3] * inv);
    o.z = pk2(a[4] * inv, a[5] * inv);
    o.w = pk2(a[6] * inv, a[7] * inv);
    h1[(size_t)n * 16 + r] = o;   // slot r: in-half cols 0-63 (r<8), out-half 64-127
}

// ---------- hop 2: h1 bf16 [NN][128] -> h2 bf16 [NN][256]; 32 thr/node, unroll 8 ----------
__global__ void gather2_kernel(const uint4* __restrict__ h1,
                               const int* __restrict__ row_in, const int* __restrict__ csr_in,
                               const int* __restrict__ row_out, const int* __restrict__ csr_out,
                               uint4* __restrict__ h2) {
    unsigned idx = blockIdx.x * 256 + threadIdx.x;   // NN*32 exactly
    unsigned n = idx >> 5, r = idx & 31;
    bool is_out = (r >= 16);
    unsigned f = r & 15;                             // uint4 slot within 16-slot h1 row
    const int* row = is_out ? row_out : row_in;
    const int* csr = is_out ? csr_out : csr_in;
    int beg = row[n], end = row[n + 1];
    float inv = 1.0f / fmaxf((float)(end - beg), 1.0f);
    float a[8] = {};
    int j = beg;
    for (; j + 7 < end; j += 8) {
        uint4 u0 = h1[(size_t)csr[j] * 16 + f];
        uint4 u1 = h1[(size_t)csr[j + 1] * 16 + f];
        uint4 u2 = h1[(size_t)csr[j + 2] * 16 + f];
        uint4 u3 = h1[(size_t)csr[j + 3] * 16 + f];
        uint4 u4 = h1[(size_t)csr[j + 4] * 16 + f];
        uint4 u5 = h1[(size_t)csr[j + 5] * 16 + f];
        uint4 u6 = h1[(size_t)csr[j + 6] * 16 + f];
        uint4 u7 = h1[(size_t)csr[j + 7] * 16 + f];
        acc8(u0, a); acc8(u1, a); acc8(u2, a); acc8(u3, a);
        acc8(u4, a); acc8(u5, a); acc8(u6, a); acc8(u7, a);
    }
    for (; j < end; ++j) acc8(h1[(size_t)csr[j] * 16 + f], a);
    uint4 o;
    o.x = pk2(a[0] * inv, a[1] * inv);
    o.y = pk2(a[2] * inv, a[3] * inv);
    o.z = pk2(a[4] * inv, a[5] * inv);
    o.w = pk2(a[6] * inv, a[7] * inv);
    h2[(size_t)n * 32 + r] = o;
}

// ---------- B prep: Bnk bf16 [n][k] 256x256; n<128 -> W[n][k], else W[n-128][256+k] ----------
__global__ void prep_b_kernel(const float* __restrict__ W, unsigned short* __restrict__ Bnk) {
    int idx = blockIdx.x * 256 + threadIdx.x;   // 65536
    int n = idx >> 8, k = idx & 255;
    float v = (n < 128) ? W[n * 512 + k] : W[(n - 128) * 512 + 256 + k];
    Bnk[idx] = f2b(v);
}

// ---------- MFMA GEMM: g[NN][256] bf16 = h2[NN][256] bf16 @ Bnk^T ----------
__global__ __launch_bounds__(256) void gemm_mfma_kernel(const unsigned short* __restrict__ A,
                                                        const unsigned short* __restrict__ Bnk,
                                                        unsigned short* __restrict__ C) {
    __shared__ unsigned short Bs[16][264];
    __shared__ unsigned short Cb[4][16][264];
    int tid = threadIdx.x;
    int wave = tid >> 6, lane = tid & 63;
    int l15 = lane & 15, q = lane >> 4;
    int m0 = blockIdx.x * 64;
    int mrow = m0 + wave * 16 + l15;
    int mclamp = min(mrow, NN - 1);
    const unsigned short* Arow = A + (size_t)mclamp * 256;
    short8 af[8];
#pragma unroll
    for (int s = 0; s < 8; ++s)
        af[s] = *(const short8*)(Arow + s * 32 + q * 8);
    floatx4 acc[16];
#pragma unroll
    for (int c = 0; c < 16; ++c) acc[c] = (floatx4){0.f, 0.f, 0.f, 0.f};
#pragma unroll
    for (int c = 0; c < 16; ++c) {
        {
            int nl = tid >> 4, seg = tid & 15;
            const uint4* srcp = (const uint4*)(Bnk + ((size_t)(16 * c + nl)) * 256 + seg * 16);
            uint4 v0 = srcp[0], v1 = srcp[1];
            *(uint4*)&Bs[nl][seg * 16] = v0;
            *(uint4*)&Bs[nl][seg * 16 + 8] = v1;
        }
        __syncthreads();
#pragma unroll
        for (int s = 0; s < 8; ++s) {
            short8 bf = *(const short8*)&Bs[l15][s * 32 + q * 8];
            acc[c] = __builtin_amdgcn_mfma_f32_16x16x32_bf16(af[s], bf, acc[c], 0, 0, 0);
        }
        __syncthreads();
    }
#pragma unroll
    for (int c = 0; c < 16; ++c)
#pragma unroll
        for (int r = 0; r < 4; ++r)
            Cb[wave][q * 4 + r][16 * c + l15] = f2b(acc[c][r]);
    __syncthreads();
#pragma unroll
    for (int i = 0; i < 8; ++i) {
        int t = i * 64 + lane;
        int rrow = t >> 5;
        int seg = t & 31;
        int m = m0 + wave * 16 + rrow;
        if (m < NN) {
            uint4 v = *(const uint4*)&Cb[wave][rrow][seg * 8];
            *(uint4*)(C + (size_t)m * 256 + seg * 8) = v;
        }
    }
}

// ---------- final hop + bias: gather g bf16, both directions; 16 thr/node, unroll 8 ----------
__global__ void final_kernel(const uint4* __restrict__ g,
                             const int* __restrict__ row_in, const int* __restrict__ csr_in,
                             const int* __restrict__ row_out, const int* __restrict__ csr_out,
                             const float4* __restrict__ b4, float4* __restrict__ out) {
    unsigned idx = blockIdx.x * 256 + threadIdx.x;   // NN*16 exactly
    unsigned n = idx >> 4, f = idx & 15;
    float a[8] = {};
    {
        int beg = row_in[n], end = row_in[n + 1];
        float inv = 1.0f / fmaxf((float)(end - beg), 1.0f);
        float s[8] = {};
        int j = beg;
        for (; j + 7 < end; j += 8) {
            uint4 u0 = g[(size_t)csr_in[j] * 32 + f];
            uint4 u1 = g[(size_t)csr_in[j + 1] * 32 + f];
            uint4 u2 = g[(size_t)csr_in[j + 2] * 32 + f];
            uint4 u3 = g[(size_t)csr_in[j + 3] * 32 + f];
            uint4 u4 = g[(size_t)csr_in[j + 4] * 32 + f];
            uint4 u5 = g[(size_t)csr_in[j + 5] * 32 + f];
            uint4 u6 = g[(size_t)csr_in[j + 6] * 32 + f];
            uint4 u7 = g[(size_t)csr_in[j + 7] * 32 + f];
            acc8(u0, s); acc8(u1, s); acc8(u2, s); acc8(u3, s);
            acc8(u4, s); acc8(u5, s); acc8(u6, s); acc8(u7, s);
        }
        for (; j < end; ++j) acc8(g[(size_t)csr_in[j] * 32 + f], s);
#pragma unroll
        for (int i = 0; i < 8; ++i) a[i] += s[i] * inv;
    }
    {
        int beg = row_out[n], end = row_out[n + 1];
        float inv = 1.0f / fmaxf((float)(end - beg), 1.0f);
        float s[8] = {};
        int j = beg;
        for (; j + 7 < end; j += 8) {
            uint4 u0 = g[(size_t)csr_out[j] * 32 + 16 + f];
            uint4 u1 = g[(size_t)csr_out[j + 1] * 32 + 16 + f];
            uint4 u2 = g[(size_t)csr_out[j + 2] * 32 + 16 + f];
            uint4 u3 = g[(size_t)csr_out[j + 3] * 32 + 16 + f];
            uint4 u4 = g[(size_t)csr_out[j + 4] * 32 + 16 + f];
            uint4 u5 = g[(size_t)csr_out[j + 5] * 32 + 16 + f];
            uint4 u6 = g[(size_t)csr_out[j + 6] * 32 + 16 + f];
            uint4 u7 = g[(size_t)csr_out[j + 7] * 32 + 16 + f];
            acc8(u0, s); acc8(u1, s); acc8(u2, s); acc8(u3, s);
            acc8(u4, s); acc8(u5, s); acc8(u6, s); acc8(u7, s);
        }
        for (; j < end; ++j) acc8(g[(size_t)csr_out[j] * 32 + 16 + f], s);
#pragma unroll
        for (int i = 0; i < 8; ++i) a[i] += s[i] * inv;
    }
    float4 b0 = b4[2 * f], b1 = b4[2 * f + 1];
    out[(size_t)n * 32 + 2 * f]     = make_float4(a[0] + b0.x, a[1] + b0.y, a[2] + b0.z, a[3] + b0.w);
    out[(size_t)n * 32 + 2 * f + 1] = make_float4(a[4] + b1.x, a[5] + b1.y, a[6] + b1.z, a[7] + b1.w);
}

extern "C" void kernel_launch(void* const* d_in, const int* in_sizes, int n_in,
                              void* d_out, int out_size, void* d_ws, size_t ws_size,
                              hipStream_t stream) {
    const float* feature = (const float*)d_in[0];
    const int*   edges   = (const int*)d_in[1];   // [2, NE]: src row then dst row
    const float* W       = (const float*)d_in[2];
    const float* b       = (const float*)d_in[3];
    const int* src = edges;
    const int* dst = edges + NE;
    float* out = (float*)d_out;

    // Workspace layout (16B-aligned chunks first). ~94 MB total.
    unsigned short* featb = (unsigned short*)d_ws;       // NN*64 bf16
    unsigned short* h1b = featb + (size_t)NN * 64;       // NN*128 bf16
    unsigned short* h2b = h1b + (size_t)NN * 128;        // NN*256 bf16
    unsigned short* gb  = h2b + (size_t)NN * 256;        // NN*256 bf16
    unsigned short* Bnk = gb + (size_t)NN * 256;         // 65536 bf16
    int2* pin  = (int2*)(Bnk + 65536);                   // NBUCK*CAP pairs
    int2* pout = pin + (size_t)NBUCK * CAP;              // NBUCK*CAP pairs
    int* csr_in  = (int*)(pout + (size_t)NBUCK * CAP);   // NE
    int* csr_out = csr_in + NE;                          // NE
    int* row_in  = csr_out + NE;                         // NN+1
    int* row_out = row_in + NN + 1;                      // NN+1
    int* gcnt_in  = row_out + NN + 1;                    // 128 (memset region start)
    int* gcnt_out = gcnt_in + 128;                       // 128 (memset region end)
    int* bb_in   = gcnt_out + 128;                       // 128
    int* bb_out  = bb_in + 128;                          // 128

    (void)hipMemsetAsync(gcnt_in, 0, 256 * sizeof(int), stream);
    featb_kernel<<<(NN * 16) / 256, 256, 0, stream>>>((const float4*)feature, (uint2*)featb);
    prep_b_kernel<<<256, 256, 0, stream>>>(W, Bnk);
    bucket_kernel<<<PA_BLOCKS, 256, 0, stream>>>(src, dst, gcnt_in, gcnt_out, pin, pout);
    bucket_scan_kernel<<<1, 64, 0, stream>>>(gcnt_in, gcnt_out, bb_in, bb_out);
    csr_build_kernel<<<2 * NBUCK, 1024, 0, stream>>>(pin, pout, gcnt_in, gcnt_out,
                                                     bb_in, bb_out, row_in, row_out,
                                                     csr_in, csr_out);

    // hop 1: featb(64 bf16) -> h1(128 bf16)
    gather1_kernel<<<(NN * 16) / 256, 256, 0, stream>>>(
        (const uint4*)featb, row_in, csr_in, row_out, csr_out, (uint4*)h1b);
    // hop 2: h1(128 bf16) -> h2(256 bf16)
    gather2_kernel<<<(NN * 32) / 256, 256, 0, stream>>>(
        (const uint4*)h1b, row_in, csr_in, row_out, csr_out, (uint4*)h2b);
    // projection (folded before hop 3): g = h2 @ Bnk^T via bf16 MFMA
    gemm_mfma_kernel<<<(NN + 63) / 64, 256, 0, stream>>>(h2b, Bnk, gb);
    // hop 3 + bias: aggregate g rows -> out (fp32)
    final_kernel<<<(NN * 16) / 256, 256, 0, stream>>>(
        (const uint4*)gb, row_in, csr_in, row_out, csr_out, (const float4*)b, (float4*)out);
}

// Round 9
// 271.401 us; speedup vs baseline: 15.8441x; 1.1386x over previous
//
#include <hip/hip_runtime.h>

// LSAGEDirected: 3 directed mean-agg hops (concat in/out) + linear projection.
// R8: revert unroll-8 regression (VGPR 48 / occ 41% -> 32 / 62%), 128-row GEMM
//     blocks, fused featb+prepB. bf16 intermediates + MFMA GEMM as R6/R7.
// N=50000 nodes, E=800000 edges: 64 ->128 ->256 --MFMA--> 256 --agg--> 128.
#define NN 50000
#define NE 800000
#define NBUCK 100
#define BUCK_N 500        // NN / NBUCK
#define CAP 10016         // per-bucket pair capacity (avg 8000)
#define PA_BLOCKS 500
#define PA_CHUNK 1600     // NE / PA_BLOCKS

typedef __attribute__((ext_vector_type(8))) short short8;
typedef __attribute__((ext_vector_type(4))) float floatx4;

// ---- bf16 helpers (ushort storage; RNE convert, shift-based upconvert) ----
__device__ __forceinline__ unsigned short f2b(float x) {
    unsigned u = __float_as_uint(x);
    return (unsigned short)((u + 0x7fffu + ((u >> 16) & 1u)) >> 16);
}
__device__ __forceinline__ unsigned pk2(float lo, float hi) {
    return (unsigned)f2b(lo) | ((unsigned)f2b(hi) << 16);
}
__device__ __forceinline__ float blo(unsigned u) { return __uint_as_float(u << 16); }
__device__ __forceinline__ float bhi(unsigned u) { return __uint_as_float(u & 0xffff0000u); }
__device__ __forceinline__ void acc8(uint4 u, float* a) {
    a[0] += blo(u.x); a[1] += bhi(u.x);
    a[2] += blo(u.y); a[3] += bhi(u.y);
    a[4] += blo(u.z); a[5] += bhi(u.z);
    a[6] += blo(u.w); a[7] += bhi(u.w);
}

// ---------- fused prep: feature fp32->bf16 (blocks 0..3124) + B fold (3125..3380) ----------
__global__ void prep_kernel(const float4* __restrict__ f32, uint2* __restrict__ fb,
                            const float* __restrict__ W, unsigned short* __restrict__ Bnk) {
    int bid = blockIdx.x;
    if (bid < 3125) {   // featb: NN*16 float4 -> uint2
        int idx = bid * 256 + threadIdx.x;
        float4 v = f32[idx];
        fb[idx] = make_uint2(pk2(v.x, v.y), pk2(v.z, v.w));
    } else {            // Bnk bf16 [n][k] 256x256; n<128 -> W[n][k], else W[n-128][256+k]
        int idx = (bid - 3125) * 256 + threadIdx.x;   // 65536
        int n = idx >> 8, k = idx & 255;
        float v = (n < 128) ? W[n * 512 + k] : W[(n - 128) * 512 + 256 + k];
        Bnk[idx] = f2b(v);
    }
}

// ---------- Phase A: bucket edges by dst (in-dir) and src (out-dir) ----------
__global__ __launch_bounds__(256) void bucket_kernel(const int* __restrict__ src,
                                                     const int* __restrict__ dst,
                                                     int* __restrict__ gcnt_in,
                                                     int* __restrict__ gcnt_out,
                                                     int2* __restrict__ pin,
                                                     int2* __restrict__ pout) {
    __shared__ int cin[NBUCK], cout[NBUCK], rin[NBUCK], rout[NBUCK];
    int tid = threadIdx.x;
    if (tid < NBUCK) { cin[tid] = 0; cout[tid] = 0; }
    __syncthreads();
    int e0 = blockIdx.x * PA_CHUNK, e1 = e0 + PA_CHUNK;
    for (int e = e0 + tid; e < e1; e += 256) {
        atomicAdd(&cin[dst[e] / BUCK_N], 1);
        atomicAdd(&cout[src[e] / BUCK_N], 1);
    }
    __syncthreads();
    if (tid < NBUCK) {
        rin[tid]  = atomicAdd(&gcnt_in[tid], cin[tid]);
        rout[tid] = atomicAdd(&gcnt_out[tid], cout[tid]);
        cin[tid] = 0; cout[tid] = 0;
    }
    __syncthreads();
    for (int e = e0 + tid; e < e1; e += 256) {
        int s = src[e], d = dst[e];
        int bi = d / BUCK_N;
        int p = atomicAdd(&cin[bi], 1);
        pin[(size_t)bi * CAP + rin[bi] + p] = make_int2(d, s);
        int bo = s / BUCK_N;
        int q = atomicAdd(&cout[bo], 1);
        pout[(size_t)bo * CAP + rout[bo] + q] = make_int2(s, d);
    }
}

// ---------- tiny scan of 100 bucket counts per direction ----------
__global__ void bucket_scan_kernel(const int* __restrict__ gcnt_in,
                                   const int* __restrict__ gcnt_out,
                                   int* __restrict__ bb_in, int* __restrict__ bb_out) {
    if (threadIdx.x == 0) {
        int run = 0;
        for (int b = 0; b < NBUCK; ++b) { bb_in[b] = run; run += gcnt_in[b]; }
    }
    if (threadIdx.x == 1) {
        int run = 0;
        for (int b = 0; b < NBUCK; ++b) { bb_out[b] = run; run += gcnt_out[b]; }
    }
}

// ---------- Phase B: per-(bucket,dir) CSR via LDS counting sort ----------
__global__ __launch_bounds__(1024) void csr_build_kernel(const int2* __restrict__ pin,
                                                         const int2* __restrict__ pout,
                                                         const int* __restrict__ gcnt_in,
                                                         const int* __restrict__ gcnt_out,
                                                         const int* __restrict__ bb_in,
                                                         const int* __restrict__ bb_out,
                                                         int* __restrict__ row_in,
                                                         int* __restrict__ row_out,
                                                         int* __restrict__ csr_in,
                                                         int* __restrict__ csr_out) {
    bool dirout = blockIdx.x >= NBUCK;
    int b = dirout ? blockIdx.x - NBUCK : blockIdx.x;
    const int2* pairs = (dirout ? pout : pin) + (size_t)b * CAP;
    int cnt  = dirout ? gcnt_out[b] : gcnt_in[b];
    int base = dirout ? bb_out[b] : bb_in[b];
    int* row = dirout ? row_out : row_in;
    int* csr = dirout ? csr_out : csr_in;
    int lo = b * BUCK_N;
    __shared__ int deg[BUCK_N], incl[BUCK_N], cur[BUCK_N];
    int tid = threadIdx.x;
    if (tid < BUCK_N) { deg[tid] = 0; cur[tid] = 0; }
    __syncthreads();
    for (int i = tid; i < cnt; i += 1024) atomicAdd(&deg[pairs[i].x - lo], 1);
    __syncthreads();
    if (tid < BUCK_N) incl[tid] = deg[tid];
    __syncthreads();
    for (int off = 1; off < BUCK_N; off <<= 1) {
        int v = 0;
        if (tid < BUCK_N && tid >= off) v = incl[tid - off];
        __syncthreads();
        if (tid < BUCK_N) incl[tid] += v;
        __syncthreads();
    }
    if (tid < BUCK_N) row[lo + tid] = base + incl[tid] - deg[tid];
    if (tid == 0 && b == NBUCK - 1) row[NN] = base + incl[BUCK_N - 1];
    __syncthreads();
    for (int i = tid; i < cnt; i += 1024) {
        int2 pr = pairs[i];
        int li = pr.x - lo;
        int pos = atomicAdd(&cur[li], 1);
        csr[base + incl[li] - deg[li] + pos] = pr.y;
    }
}

// ---------- hop 1: featb bf16 [NN][64] -> h1 bf16 [NN][128]; 16 thr/node, unroll 4 ----------
__global__ void gather1_kernel(const uint4* __restrict__ feat,
                               const int* __restrict__ row_in, const int* __restrict__ csr_in,
                               const int* __restrict__ row_out, const int* __restrict__ csr_out,
                               uint4* __restrict__ h1) {
    unsigned idx = blockIdx.x * 256 + threadIdx.x;   // NN*16 exactly
    unsigned n = idx >> 4, r = idx & 15;             // r: 0-7 in-dir, 8-15 out-dir
    bool is_out = (r >= 8);
    unsigned f = r & 7;                              // uint4 slot (8 bf16 cols) of featb row
    const int* row = is_out ? row_out : row_in;
    const int* csr = is_out ? csr_out : csr_in;
    int beg = row[n], end = row[n + 1];
    float inv = 1.0f / fmaxf((float)(end - beg), 1.0f);
    float a[8] = {};
    int j = beg;
    for (; j + 3 < end; j += 4) {
        uint4 u0 = feat[(size_t)csr[j] * 8 + f];
        uint4 u1 = feat[(size_t)csr[j + 1] * 8 + f];
        uint4 u2 = feat[(size_t)csr[j + 2] * 8 + f];
        uint4 u3 = feat[(size_t)csr[j + 3] * 8 + f];
        acc8(u0, a); acc8(u1, a); acc8(u2, a); acc8(u3, a);
    }
    for (; j < end; ++j) acc8(feat[(size_t)csr[j] * 8 + f], a);
    uint4 o;
    o.x = pk2(a[0] * inv, a[1] * inv);
    o.y = pk2(a[2] * inv, a[3] * inv);
    o.z = pk2(a[4] * inv, a[5] * inv);
    o.w = pk2(a[6] * inv, a[7] * inv);
    h1[(size_t)n * 16 + r] = o;
}

// ---------- hop 2: h1 bf16 [NN][128] -> h2 bf16 [NN][256]; 32 thr/node, unroll 4 ----------
__global__ void gather2_kernel(const uint4* __restrict__ h1,
                               const int* __restrict__ row_in, const int* __restrict__ csr_in,
                               const int* __restrict__ row_out, const int* __restrict__ csr_out,
                               uint4* __restrict__ h2) {
    unsigned idx = blockIdx.x * 256 + threadIdx.x;   // NN*32 exactly
    unsigned n = idx >> 5, r = idx & 31;
    bool is_out = (r >= 16);
    unsigned f = r & 15;                             // uint4 slot within 16-slot h1 row
    const int* row = is_out ? row_out : row_in;
    const int* csr = is_out ? csr_out : csr_in;
    int beg = row[n], end = row[n + 1];
    float inv = 1.0f / fmaxf((float)(end - beg), 1.0f);
    float a[8] = {};
    int j = beg;
    for (; j + 3 < end; j += 4) {
        uint4 u0 = h1[(size_t)csr[j] * 16 + f];
        uint4 u1 = h1[(size_t)csr[j + 1] * 16 + f];
        uint4 u2 = h1[(size_t)csr[j + 2] * 16 + f];
        uint4 u3 = h1[(size_t)csr[j + 3] * 16 + f];
        acc8(u0, a); acc8(u1, a); acc8(u2, a); acc8(u3, a);
    }
    for (; j < end; ++j) acc8(h1[(size_t)csr[j] * 16 + f], a);
    uint4 o;
    o.x = pk2(a[0] * inv, a[1] * inv);
    o.y = pk2(a[2] * inv, a[3] * inv);
    o.z = pk2(a[4] * inv, a[5] * inv);
    o.w = pk2(a[6] * inv, a[7] * inv);
    h2[(size_t)n * 32 + r] = o;
}

// ---------- MFMA GEMM: g[NN][256] bf16 = h2[NN][256] bf16 @ Bnk^T ----------
// 128 rows/block (2 m-tiles per wave): halves B restaging + barriers per output.
__global__ __launch_bounds__(256) void gemm_mfma_kernel(const unsigned short* __restrict__ A,
                                                        const unsigned short* __restrict__ Bnk,
                                                        unsigned short* __restrict__ C) {
    __shared__ unsigned short Bs[16][264];
    __shared__ unsigned short Cb[4][16][264];
    int tid = threadIdx.x;
    int wave = tid >> 6, lane = tid & 63;
    int l15 = lane & 15, q = lane >> 4;
    int m0 = blockIdx.x * 128;
    short8 af[2][8];
#pragma unroll
    for (int t = 0; t < 2; ++t) {
        int mrow = m0 + (wave + 4 * t) * 16 + l15;
        const unsigned short* Arow = A + (size_t)min(mrow, NN - 1) * 256;
#pragma unroll
        for (int s = 0; s < 8; ++s)
            af[t][s] = *(const short8*)(Arow + s * 32 + q * 8);
    }
    floatx4 acc[2][16];
#pragma unroll
    for (int t = 0; t < 2; ++t)
#pragma unroll
        for (int c = 0; c < 16; ++c) acc[t][c] = (floatx4){0.f, 0.f, 0.f, 0.f};
#pragma unroll
    for (int c = 0; c < 16; ++c) {
        {   // stage B rows 16c..16c+16 (512B each); thread t: row t>>4, 32B seg
            int nl = tid >> 4, seg = tid & 15;
            const uint4* srcp = (const uint4*)(Bnk + ((size_t)(16 * c + nl)) * 256 + seg * 16);
            uint4 v0 = srcp[0], v1 = srcp[1];
            *(uint4*)&Bs[nl][seg * 16] = v0;
            *(uint4*)&Bs[nl][seg * 16 + 8] = v1;
        }
        __syncthreads();
#pragma unroll
        for (int s = 0; s < 8; ++s) {
            short8 bf = *(const short8*)&Bs[l15][s * 32 + q * 8];
            acc[0][c] = __builtin_amdgcn_mfma_f32_16x16x32_bf16(af[0][s], bf, acc[0][c], 0, 0, 0);
            acc[1][c] = __builtin_amdgcn_mfma_f32_16x16x32_bf16(af[1][s], bf, acc[1][c], 0, 0, 0);
        }
        __syncthreads();
    }
    // epilogue per m-tile strip: D layout col=l15,row=q*4+r -> LDS -> coalesced stores
#pragma unroll
    for (int t = 0; t < 2; ++t) {
#pragma unroll
        for (int c = 0; c < 16; ++c)
#pragma unroll
            for (int r = 0; r < 4; ++r)
                Cb[wave][q * 4 + r][16 * c + l15] = f2b(acc[t][c][r]);
        __syncthreads();
#pragma unroll
        for (int i = 0; i < 8; ++i) {
            int tt = i * 64 + lane;
            int rrow = tt >> 5;
            int seg = tt & 31;
            int m = m0 + (wave + 4 * t) * 16 + rrow;
            if (m < NN) {
                uint4 v = *(const uint4*)&Cb[wave][rrow][seg * 8];
                *(uint4*)(C + (size_t)m * 256 + seg * 8) = v;
            }
        }
        __syncthreads();
    }
}

// ---------- final hop + bias: gather g bf16, both directions; 16 thr/node, unroll 4 ----------
__global__ void final_kernel(const uint4* __restrict__ g,
                             const int* __restrict__ row_in, const int* __restrict__ csr_in,
                             const int* __restrict__ row_out, const int* __restrict__ csr_out,
                             const float4* __restrict__ b4, float4* __restrict__ out) {
    unsigned idx = blockIdx.x * 256 + threadIdx.x;   // NN*16 exactly
    unsigned n = idx >> 4, f = idx & 15;
    float a[8] = {};
    {
        int beg = row_in[n], end = row_in[n + 1];
        float inv = 1.0f / fmaxf((float)(end - beg), 1.0f);
        float s[8] = {};
        int j = beg;
        for (; j + 3 < end; j += 4) {
            uint4 u0 = g[(size_t)csr_in[j] * 32 + f];
            uint4 u1 = g[(size_t)csr_in[j + 1] * 32 + f];
            uint4 u2 = g[(size_t)csr_in[j + 2] * 32 + f];
            uint4 u3 = g[(size_t)csr_in[j + 3] * 32 + f];
            acc8(u0, s); acc8(u1, s); acc8(u2, s); acc8(u3, s);
        }
        for (; j < end; ++j) acc8(g[(size_t)csr_in[j] * 32 + f], s);
#pragma unroll
        for (int i = 0; i < 8; ++i) a[i] += s[i] * inv;
    }
    {
        int beg = row_out[n], end = row_out[n + 1];
        float inv = 1.0f / fmaxf((float)(end - beg), 1.0f);
        float s[8] = {};
        int j = beg;
        for (; j + 3 < end; j += 4) {
            uint4 u0 = g[(size_t)csr_out[j] * 32 + 16 + f];
            uint4 u1 = g[(size_t)csr_out[j + 1] * 32 + 16 + f];
            uint4 u2 = g[(size_t)csr_out[j + 2] * 32 + 16 + f];
            uint4 u3 = g[(size_t)csr_out[j + 3] * 32 + 16 + f];
            acc8(u0, s); acc8(u1, s); acc8(u2, s); acc8(u3, s);
        }
        for (; j < end; ++j) acc8(g[(size_t)csr_out[j] * 32 + 16 + f], s);
#pragma unroll
        for (int i = 0; i < 8; ++i) a[i] += s[i] * inv;
    }
    float4 b0 = b4[2 * f], b1 = b4[2 * f + 1];
    out[(size_t)n * 32 + 2 * f]     = make_float4(a[0] + b0.x, a[1] + b0.y, a[2] + b0.z, a[3] + b0.w);
    out[(size_t)n * 32 + 2 * f + 1] = make_float4(a[4] + b1.x, a[5] + b1.y, a[6] + b1.z, a[7] + b1.w);
}

extern "C" void kernel_launch(void* const* d_in, const int* in_sizes, int n_in,
                              void* d_out, int out_size, void* d_ws, size_t ws_size,
                              hipStream_t stream) {
    const float* feature = (const float*)d_in[0];
    const int*   edges   = (const int*)d_in[1];   // [2, NE]: src row then dst row
    const float* W       = (const float*)d_in[2];
    const float* b       = (const float*)d_in[3];
    const int* src = edges;
    const int* dst = edges + NE;
    float* out = (float*)d_out;

    // Workspace layout (16B-aligned chunks first). ~94 MB total.
    unsigned short* featb = (unsigned short*)d_ws;       // NN*64 bf16
    unsigned short* h1b = featb + (size_t)NN * 64;       // NN*128 bf16
    unsigned short* h2b = h1b + (size_t)NN * 128;        // NN*256 bf16
    unsigned short* gb  = h2b + (size_t)NN * 256;        // NN*256 bf16
    unsigned short* Bnk = gb + (size_t)NN * 256;         // 65536 bf16
    int2* pin  = (int2*)(Bnk + 65536);                   // NBUCK*CAP pairs
    int2* pout = pin + (size_t)NBUCK * CAP;              // NBUCK*CAP pairs
    int* csr_in  = (int*)(pout + (size_t)NBUCK * CAP);   // NE
    int* csr_out = csr_in + NE;                          // NE
    int* row_in  = csr_out + NE;                         // NN+1
    int* row_out = row_in + NN + 1;                      // NN+1
    int* gcnt_in  = row_out + NN + 1;                    // 128 (memset region start)
    int* gcnt_out = gcnt_in + 128;                       // 128 (memset region end)
    int* bb_in   = gcnt_out + 128;                       // 128
    int* bb_out  = bb_in + 128;                          // 128

    (void)hipMemsetAsync(gcnt_in, 0, 256 * sizeof(int), stream);
    prep_kernel<<<3125 + 256, 256, 0, stream>>>((const float4*)feature, (uint2*)featb, W, Bnk);
    bucket_kernel<<<PA_BLOCKS, 256, 0, stream>>>(src, dst, gcnt_in, gcnt_out, pin, pout);
    bucket_scan_kernel<<<1, 64, 0, stream>>>(gcnt_in, gcnt_out, bb_in, bb_out);
    csr_build_kernel<<<2 * NBUCK, 1024, 0, stream>>>(pin, pout, gcnt_in, gcnt_out,
                                                     bb_in, bb_out, row_in, row_out,
                                                     csr_in, csr_out);

    // hop 1: featb(64 bf16) -> h1(128 bf16)
    gather1_kernel<<<(NN * 16) / 256, 256, 0, stream>>>(
        (const uint4*)featb, row_in, csr_in, row_out, csr_out, (uint4*)h1b);
    // hop 2: h1(128 bf16) -> h2(256 bf16)
    gather2_kernel<<<(NN * 32) / 256, 256, 0, stream>>>(
        (const uint4*)h1b, row_in, csr_in, row_out, csr_out, (uint4*)h2b);
    // projection (folded before hop 3): g = h2 @ Bnk^T via bf16 MFMA, 128 rows/block
    gemm_mfma_kernel<<<(NN + 127) / 128, 256, 0, stream>>>(h2b, Bnk, gb);
    // hop 3 + bias: aggregate g rows -> out (fp32)
    final_kernel<<<(NN * 16) / 256, 256, 0, stream>>>(
        (const uint4*)gb, row_in, csr_in, row_out, csr_out, (const float4*)b, (float4*)out);
}